// Round 1
// baseline (240.530 us; speedup 1.0000x reference)
//
#include <hip/hip_runtime.h>

typedef unsigned int u32;
typedef unsigned short u16;
typedef __attribute__((ext_vector_type(4))) float f32x4;
typedef __attribute__((ext_vector_type(8))) short s16x8;

#define S_LEN 2048
#define DMODEL 2048
#define NH 16
#define NKV 4
#define HD 128
#define WIN 512

__device__ __forceinline__ u16 f2bf(float f) {
  union { float f; u32 u; } v; v.f = f;
  u32 r = v.u + 0x7FFFu + ((v.u >> 16) & 1u);
  return (u16)(r >> 16);
}
__device__ __forceinline__ float bf2f(u16 h) {
  union { u32 u; float f; } v; v.u = ((u32)h) << 16;
  return v.f;
}

__device__ __forceinline__ void async16(const void* g, void* l) {
  __builtin_amdgcn_global_load_lds((const __attribute__((address_space(1))) void*)g,
                                   (__attribute__((address_space(3))) void*)l, 16, 0, 0);
}

// ---------------- prep kernels ----------------

__global__ void k_rope_table(float2* __restrict__ cs) {
  int s = blockIdx.x, d = threadIdx.x;  // d in [0,64)
  float invf = expf(-((float)(2 * d) / (float)HD) * logf(10000.0f));
  float fr = (float)s * invf;
  float sv, cv;
  sincosf(fr, &sv, &cv);
  cs[s * 64 + d] = make_float2(cv, sv);
}

__global__ void k_convert_bf16(const float* __restrict__ src, u16* __restrict__ dst, int n4) {
  int i = blockIdx.x * blockDim.x + threadIdx.x;
  if (i >= n4) return;
  float4 v = ((const float4*)src)[i];
  ushort4 o;
  o.x = f2bf(v.x); o.y = f2bf(v.y); o.z = f2bf(v.z); o.w = f2bf(v.w);
  ((ushort4*)dst)[i] = o;
}

// dst[n*K + k] = bf16(src[k*N + n]);  grid=(N/32, K/32), block=(32,8)
__global__ __launch_bounds__(256) void k_transpose_bf16(const float* __restrict__ src,
                                                        u16* __restrict__ dst, int K, int N) {
  __shared__ float tile[32][33];
  int tx = threadIdx.x, ty = threadIdx.y;
  int n0 = blockIdx.x * 32, k0 = blockIdx.y * 32;
#pragma unroll
  for (int i = 0; i < 4; ++i)
    tile[ty + 8 * i][tx] = src[(size_t)(k0 + ty + 8 * i) * N + n0 + tx];
  __syncthreads();
#pragma unroll
  for (int i = 0; i < 4; ++i)
    dst[(size_t)(n0 + ty + 8 * i) * K + k0 + tx] = f2bf(tile[tx][ty + 8 * i]);
}

__global__ void k_rope_apply(u16* __restrict__ q, const float2* __restrict__ cs, int nrows) {
  int i = blockIdx.x * blockDim.x + threadIdx.x;
  if (i >= nrows * 64) return;
  int row = i >> 6, d = i & 63;
  int s = row & (S_LEN - 1);
  float2 c = cs[s * 64 + d];
  u16* p = q + (size_t)row * HD;
  float a = bf2f(p[d]), b = bf2f(p[d + 64]);
  p[d]      = f2bf(a * c.x - b * c.y);
  p[d + 64] = f2bf(b * c.x + a * c.y);
}

// ---------------- GEMM ----------------
// A [M][K] bf16 row-major, BT [N][K] bf16. 128x128 tile, BK=32, 4 waves (2x2 of 64x64).
// MODE 0: scatter epilogue -> qr[h][s][d], kr[h][s][d], vt[h][d][s]
// MODE 1: plain fp32 C[M][N]

__device__ __forceinline__ u32 swz_byte(u32 row, u32 slot) {
  return row * 64u + ((slot ^ ((row ^ (row >> 2)) & 3u)) * 16u);
}

template <int MODE>
__global__ __launch_bounds__(256) void k_gemm(const u16* __restrict__ A, const u16* __restrict__ BT,
                                              float* __restrict__ Cf, int K, int N,
                                              u16* __restrict__ qr, u16* __restrict__ kr,
                                              u16* __restrict__ vt) {
  __shared__ u16 As[128 * 32];
  __shared__ u16 Bs[128 * 32];
  const int t = threadIdx.x;
  const int l = t & 63, w = t >> 6;
  const int lg = l >> 4, ll = l & 15;
  const int m0 = blockIdx.x * 128, n0 = blockIdx.y * 128;
  const int wm = (w >> 1) * 64, wn = (w & 1) * 64;

  f32x4 acc[4][4];
#pragma unroll
  for (int i = 0; i < 4; ++i)
#pragma unroll
    for (int j = 0; j < 4; ++j) acc[i][j] = (f32x4){0.f, 0.f, 0.f, 0.f};

  for (int k0 = 0; k0 < K; k0 += 32) {
    __syncthreads();
#pragma unroll
    for (int i = 0; i < 2; ++i) {
      u32 u = (u32)t * 16u + (u32)i * 4096u;
      u32 row = u >> 6, slot = (u >> 4) & 3u;
      u32 kb = (slot ^ ((row ^ (row >> 2)) & 3u)) * 8u;  // element offset of 16B slot
      async16(A + (size_t)(m0 + row) * K + k0 + kb, (char*)As + u);
      async16(BT + (size_t)(n0 + row) * K + k0 + kb, (char*)Bs + u);
    }
    asm volatile("s_waitcnt vmcnt(0)" ::: "memory");
    __syncthreads();

    s16x8 af[4], bfr[4];
#pragma unroll
    for (int mt = 0; mt < 4; ++mt) {
      u32 r = (u32)(wm + mt * 16 + ll);
      af[mt] = *(const s16x8*)((const char*)As + swz_byte(r, (u32)lg));
    }
#pragma unroll
    for (int nt = 0; nt < 4; ++nt) {
      u32 r = (u32)(wn + nt * 16 + ll);
      bfr[nt] = *(const s16x8*)((const char*)Bs + swz_byte(r, (u32)lg));
    }
#pragma unroll
    for (int mt = 0; mt < 4; ++mt)
#pragma unroll
      for (int nt = 0; nt < 4; ++nt)
        acc[mt][nt] = __builtin_amdgcn_mfma_f32_16x16x32_bf16(af[mt], bfr[nt], acc[mt][nt], 0, 0, 0);
  }

  if (MODE == 1) {
#pragma unroll
    for (int mt = 0; mt < 4; ++mt) {
      int srow = m0 + wm + mt * 16 + lg * 4;
#pragma unroll
      for (int nt = 0; nt < 4; ++nt) {
        int col = n0 + wn + nt * 16 + ll;
        f32x4 a = acc[mt][nt];
#pragma unroll
        for (int j = 0; j < 4; ++j) Cf[(size_t)(srow + j) * N + col] = a[j];
      }
    }
  } else {
#pragma unroll
    for (int nt = 0; nt < 4; ++nt) {
      int cb = n0 + wn + nt * 16;  // wave-uniform
#pragma unroll
      for (int mt = 0; mt < 4; ++mt) {
        int srow = m0 + wm + mt * 16 + lg * 4;
        f32x4 a = acc[mt][nt];
        if (cb < 2048) {
          int hh = cb >> 7, d = (cb & 127) + ll;
          u16* p = qr + ((size_t)hh * S_LEN) * HD + d;
#pragma unroll
          for (int j = 0; j < 4; ++j) p[(size_t)(srow + j) * HD] = f2bf(a[j]);
        } else if (cb < 2560) {
          int hh = (cb - 2048) >> 7, d = ((cb - 2048) & 127) + ll;
          u16* p = kr + ((size_t)hh * S_LEN) * HD + d;
#pragma unroll
          for (int j = 0; j < 4; ++j) p[(size_t)(srow + j) * HD] = f2bf(a[j]);
        } else {
          int hh = (cb - 2560) >> 7, d = ((cb - 2560) & 127) + ll;
          ushort4 pk;
          pk.x = f2bf(a[0]); pk.y = f2bf(a[1]); pk.z = f2bf(a[2]); pk.w = f2bf(a[3]);
          *(ushort4*)(vt + ((size_t)hh * HD + d) * S_LEN + srow) = pk;
        }
      }
    }
  }
}

// ---------------- attention ----------------
// grid (S/64, NH), block 256. Wave w handles q rows [qs, qs+16).
__global__ __launch_bounds__(256) void k_attn(const u16* __restrict__ qr, const u16* __restrict__ kr,
                                              const u16* __restrict__ vt, const float* __restrict__ lam,
                                              u16* __restrict__ ao) {
  __shared__ u16 P[4][16 * 56];  // per-wave P tile, row stride 56 (112B, 16B-aligned, 2-way banks)
  const int t = threadIdx.x;
  const int l = t & 63, w = t >> 6;
  const int lg = l >> 4, ll = l & 15;
  const int h = blockIdx.y;
  const int qs = blockIdx.x * 64 + w * 16;
  const int hk = h >> 2;
  const float lm = lam[h];

  const u16* Qp = qr + ((size_t)h * S_LEN + qs) * HD;
  const u16* Kp = kr + (size_t)hk * S_LEN * HD;
  const u16* Vp = vt + (size_t)hk * HD * S_LEN;

  s16x8 qa[4];
#pragma unroll
  for (int i = 0; i < 4; ++i)
    qa[i] = *(const s16x8*)(Qp + (size_t)ll * HD + i * 32 + lg * 8);

  int kbeg = qs - (WIN - 1);
  if (kbeg < 0) kbeg = 0;
  kbeg &= ~31;
  const int kend = qs + 15;

  float m1[4], z1[4], m2[4], z2[4];
#pragma unroll
  for (int j = 0; j < 4; ++j) { m1[j] = -1e30f; m2[j] = -1e30f; z1[j] = 0.f; z2[j] = 0.f; }

  const f32x4 zero = {0.f, 0.f, 0.f, 0.f};

  // ---- pass 1: softmax stats for both halves ----
  for (int c = kbeg; c <= kend; c += 32) {
    f32x4 s1[2], s2[2];
#pragma unroll
    for (int kt = 0; kt < 2; ++kt) {
      const u16* kp = Kp + (size_t)(c + kt * 16 + ll) * HD + lg * 8;
      s16x8 b0 = *(const s16x8*)(kp);
      s16x8 b1 = *(const s16x8*)(kp + 32);
      s16x8 b2 = *(const s16x8*)(kp + 64);
      s16x8 b3 = *(const s16x8*)(kp + 96);
      f32x4 a = __builtin_amdgcn_mfma_f32_16x16x32_bf16(qa[0], b0, zero, 0, 0, 0);
      a = __builtin_amdgcn_mfma_f32_16x16x32_bf16(qa[1], b1, a, 0, 0, 0);
      f32x4 b = __builtin_amdgcn_mfma_f32_16x16x32_bf16(qa[2], b2, zero, 0, 0, 0);
      b = __builtin_amdgcn_mfma_f32_16x16x32_bf16(qa[3], b3, b, 0, 0, 0);
      int key = c + kt * 16 + ll;
#pragma unroll
      for (int j = 0; j < 4; ++j) {
        int row = qs + lg * 4 + j;
        bool ok = (key <= row) && (key > row - WIN);
        s1[kt][j] = ok ? a[j] * 0.125f : -1e30f;
        s2[kt][j] = ok ? b[j] * 0.125f : -1e30f;
      }
    }
#pragma unroll
    for (int j = 0; j < 4; ++j) {
      float c1 = fmaxf(s1[0][j], s1[1][j]);
      float c2 = fmaxf(s2[0][j], s2[1][j]);
#pragma unroll
      for (int mk = 1; mk < 16; mk <<= 1) {
        c1 = fmaxf(c1, __shfl_xor(c1, mk, 64));
        c2 = fmaxf(c2, __shfl_xor(c2, mk, 64));
      }
      float n1 = fmaxf(m1[j], c1), n2 = fmaxf(m2[j], c2);
      float p1 = (s1[0][j] > -1e29f ? __expf(s1[0][j] - n1) : 0.f) +
                 (s1[1][j] > -1e29f ? __expf(s1[1][j] - n1) : 0.f);
      float p2 = (s2[0][j] > -1e29f ? __expf(s2[0][j] - n2) : 0.f) +
                 (s2[1][j] > -1e29f ? __expf(s2[1][j] - n2) : 0.f);
#pragma unroll
      for (int mk = 1; mk < 16; mk <<= 1) {
        p1 += __shfl_xor(p1, mk, 64);
        p2 += __shfl_xor(p2, mk, 64);
      }
      z1[j] = z1[j] * __expf(m1[j] - n1) + p1;
      z2[j] = z2[j] * __expf(m2[j] - n2) + p2;
      m1[j] = n1; m2[j] = n2;
    }
  }

  float rz1[4], rz2[4];
#pragma unroll
  for (int j = 0; j < 4; ++j) { rz1[j] = 1.f / z1[j]; rz2[j] = 1.f / z2[j]; }

  // ---- pass 2: recompute scores, diff-combine, PV ----
  f32x4 o[8];
#pragma unroll
  for (int dt = 0; dt < 8; ++dt) o[dt] = zero;
  float ds[4] = {0.f, 0.f, 0.f, 0.f};

  for (int c = kbeg; c <= kend; c += 32) {
    f32x4 s1[2], s2[2];
#pragma unroll
    for (int kt = 0; kt < 2; ++kt) {
      const u16* kp = Kp + (size_t)(c + kt * 16 + ll) * HD + lg * 8;
      s16x8 b0 = *(const s16x8*)(kp);
      s16x8 b1 = *(const s16x8*)(kp + 32);
      s16x8 b2 = *(const s16x8*)(kp + 64);
      s16x8 b3 = *(const s16x8*)(kp + 96);
      f32x4 a = __builtin_amdgcn_mfma_f32_16x16x32_bf16(qa[0], b0, zero, 0, 0, 0);
      a = __builtin_amdgcn_mfma_f32_16x16x32_bf16(qa[1], b1, a, 0, 0, 0);
      f32x4 b = __builtin_amdgcn_mfma_f32_16x16x32_bf16(qa[2], b2, zero, 0, 0, 0);
      b = __builtin_amdgcn_mfma_f32_16x16x32_bf16(qa[3], b3, b, 0, 0, 0);
      int key = c + kt * 16 + ll;
#pragma unroll
      for (int j = 0; j < 4; ++j) {
        int row = qs + lg * 4 + j;
        bool ok = (key <= row) && (key > row - WIN);
        s1[kt][j] = ok ? a[j] * 0.125f : -1e30f;
        s2[kt][j] = ok ? b[j] * 0.125f : -1e30f;
      }
    }
#pragma unroll
    for (int kt = 0; kt < 2; ++kt) {
#pragma unroll
      for (int j = 0; j < 4; ++j) {
        float a1 = s1[kt][j] > -1e29f ? __expf(s1[kt][j] - m1[j]) * rz1[j] : 0.f;
        float a2 = s2[kt][j] > -1e29f ? __expf(s2[kt][j] - m2[j]) * rz2[j] : 0.f;
        float d = fmaxf(a1 - lm * a2, 0.f);
        ds[j] += d;
        P[w][(lg * 4 + j) * 56 + kt * 16 + ll] = f2bf(d);
      }
    }
    // per-wave LDS RAW: compiler inserts lgkmcnt waits; no cross-wave sharing.
    s16x8 pf = *(const s16x8*)((const u16*)P[w] + ll * 56 + lg * 8);
#pragma unroll
    for (int dt = 0; dt < 8; ++dt) {
      const u16* vp = Vp + (size_t)(dt * 16 + ll) * S_LEN + c + lg * 8;
      s16x8 vf = *(const s16x8*)vp;
      o[dt] = __builtin_amdgcn_mfma_f32_16x16x32_bf16(pf, vf, o[dt], 0, 0, 0);
    }
  }

#pragma unroll
  for (int j = 0; j < 4; ++j) {
    float v = ds[j];
#pragma unroll
    for (int mk = 1; mk < 16; mk <<= 1) v += __shfl_xor(v, mk, 64);
    ds[j] = 1.f / (v + 1e-6f);
  }
#pragma unroll
  for (int dt = 0; dt < 8; ++dt) {
#pragma unroll
    for (int j = 0; j < 4; ++j) {
      int srow = qs + lg * 4 + j;
      ao[(size_t)srow * DMODEL + h * HD + dt * 16 + ll] = f2bf(o[dt][j] * ds[j]);
    }
  }
}

// ---------------- launch ----------------

extern "C" void kernel_launch(void* const* d_in, const int* in_sizes, int n_in,
                              void* d_out, int out_size, void* d_ws, size_t ws_size,
                              hipStream_t stream) {
  const float* x = (const float*)d_in[0];
  const float* Wq = (const float*)d_in[1];
  const float* Wk = (const float*)d_in[2];
  const float* Wv = (const float*)d_in[3];
  const float* Wo = (const float*)d_in[4];
  const float* lam = (const float*)d_in[5];
  float* out = (float*)d_out;

  char* ws = (char*)d_ws;
  u16* xb = (u16*)(ws);                               // 8 MB  [2048][2048]
  u16* WT = (u16*)(ws + (8u << 20));                  // 12 MB [3072][2048] (Wq^T|Wk^T|Wv^T)
  u16* WoT = (u16*)(ws + (20u << 20));                // 8 MB  [2048][2048]
  u16* qr = (u16*)(ws + (28u << 20));                 // 8 MB  [16][2048][128]
  u16* kr = (u16*)(ws + (36u << 20));                 // 2 MB  [4][2048][128]
  u16* vt = (u16*)(ws + (38u << 20));                 // 2 MB  [4][128][2048]
  u16* ao = (u16*)(ws + (40u << 20));                 // 8 MB  [2048][2048]
  float2* cs = (float2*)(ws + (48u << 20));           // 1 MB  [2048][64]

  k_rope_table<<<S_LEN, 64, 0, stream>>>(cs);
  k_convert_bf16<<<4096, 256, 0, stream>>>(x, xb, (S_LEN * DMODEL) / 4);

  dim3 tb(32, 8);
  k_transpose_bf16<<<dim3(2048 / 32, 2048 / 32), tb, 0, stream>>>(Wq, WT, 2048, 2048);
  k_transpose_bf16<<<dim3(512 / 32, 2048 / 32), tb, 0, stream>>>(Wk, WT + (size_t)2048 * 2048, 2048, 512);
  k_transpose_bf16<<<dim3(512 / 32, 2048 / 32), tb, 0, stream>>>(Wv, WT + (size_t)2560 * 2048, 2048, 512);
  k_transpose_bf16<<<dim3(2048 / 32, 2048 / 32), tb, 0, stream>>>(Wo, WoT, 2048, 2048);

  k_gemm<0><<<dim3(16, 24), 256, 0, stream>>>(xb, WT, nullptr, 2048, 3072, qr, kr, vt);

  k_rope_apply<<<(NH * S_LEN * 64) / 256, 256, 0, stream>>>(qr, cs, NH * S_LEN);
  k_rope_apply<<<(NKV * S_LEN * 64) / 256, 256, 0, stream>>>(kr, cs, NKV * S_LEN);

  k_attn<<<dim3(S_LEN / 64, NH), 256, 0, stream>>>(qr, kr, vt, lam, ao);

  k_gemm<1><<<dim3(16, 16), 256, 0, stream>>>(ao, WoT, out, 2048, 2048, nullptr, nullptr, nullptr);
}

// Round 2
// 231.340 us; speedup vs baseline: 1.0397x; 1.0397x over previous
//
#include <hip/hip_runtime.h>

typedef unsigned int u32;
typedef unsigned short u16;
typedef __attribute__((ext_vector_type(4))) float f32x4;
typedef __attribute__((ext_vector_type(8))) short s16x8;

#define S_LEN 2048
#define DMODEL 2048
#define NH 16
#define NKV 4
#define HD 128
#define WIN 512
// 0.125 (1/sqrt(64)) * log2(e): folds score scale + exp2-domain conversion into Q
#define QSCALE 0.18033688011112042f

__device__ __forceinline__ u16 f2bf(float f) {
  union { float f; u32 u; } v; v.f = f;
  u32 r = v.u + 0x7FFFu + ((v.u >> 16) & 1u);
  return (u16)(r >> 16);
}
__device__ __forceinline__ float bf2f(u16 h) {
  union { u32 u; float f; } v; v.u = ((u32)h) << 16;
  return v.f;
}

__device__ __forceinline__ void async16(const void* g, void* l) {
  __builtin_amdgcn_global_load_lds((const __attribute__((address_space(1))) void*)g,
                                   (__attribute__((address_space(3))) void*)l, 16, 0, 0);
}

// ---------------- prep kernels ----------------

__global__ void k_rope_table(float2* __restrict__ cs) {
  int s = blockIdx.x, d = threadIdx.x;  // d in [0,64)
  float invf = expf(-((float)(2 * d) / (float)HD) * logf(10000.0f));
  float fr = (float)s * invf;
  float sv, cv;
  sincosf(fr, &sv, &cv);
  cs[s * 64 + d] = make_float2(cv, sv);
}

__global__ void k_convert_bf16(const float* __restrict__ src, u16* __restrict__ dst, int n4) {
  int i = blockIdx.x * blockDim.x + threadIdx.x;
  if (i >= n4) return;
  float4 v = ((const float4*)src)[i];
  ushort4 o;
  o.x = f2bf(v.x); o.y = f2bf(v.y); o.z = f2bf(v.z); o.w = f2bf(v.w);
  ((ushort4*)dst)[i] = o;
}

// dst[n*K + k] = bf16(src[k*N + n]);  grid=(N/32, K/32), block=(32,8)
__global__ __launch_bounds__(256) void k_transpose_bf16(const float* __restrict__ src,
                                                        u16* __restrict__ dst, int K, int N) {
  __shared__ float tile[32][33];
  int tx = threadIdx.x, ty = threadIdx.y;
  int n0 = blockIdx.x * 32, k0 = blockIdx.y * 32;
#pragma unroll
  for (int i = 0; i < 4; ++i)
    tile[ty + 8 * i][tx] = src[(size_t)(k0 + ty + 8 * i) * N + n0 + tx];
  __syncthreads();
#pragma unroll
  for (int i = 0; i < 4; ++i)
    dst[(size_t)(n0 + ty + 8 * i) * K + k0 + tx] = f2bf(tile[tx][ty + 8 * i]);
}

// rope in-place on [nrows][128] bf16, row s = row & (S_LEN-1); optional uniform scale.
__global__ void k_rope_apply(u16* __restrict__ q, const float2* __restrict__ cs, int nrows,
                             float scale) {
  int i = blockIdx.x * blockDim.x + threadIdx.x;
  if (i >= nrows * 64) return;
  int row = i >> 6, d = i & 63;
  int s = row & (S_LEN - 1);
  float2 c = cs[s * 64 + d];
  u16* p = q + (size_t)row * HD;
  float a = bf2f(p[d]), b = bf2f(p[d + 64]);
  p[d]      = f2bf((a * c.x - b * c.y) * scale);
  p[d + 64] = f2bf((b * c.x + a * c.y) * scale);
}

// ---------------- GEMM ----------------
// A [M][K] bf16 row-major, BT [N][K] bf16. 128x128 tile, BK=32, 4 waves (2x2 of 64x64).
// MODE 0: scatter epilogue -> qr[h][s][d], kr[h][s][d], vt[h][d][s]
// MODE 1: plain fp32 C[M][N]

__device__ __forceinline__ u32 swz_byte(u32 row, u32 slot) {
  return row * 64u + ((slot ^ ((row ^ (row >> 2)) & 3u)) * 16u);
}

template <int MODE>
__global__ __launch_bounds__(256) void k_gemm(const u16* __restrict__ A, const u16* __restrict__ BT,
                                              float* __restrict__ Cf, int K, int N,
                                              u16* __restrict__ qr, u16* __restrict__ kr,
                                              u16* __restrict__ vt) {
  __shared__ u16 As[128 * 32];
  __shared__ u16 Bs[128 * 32];
  const int t = threadIdx.x;
  const int l = t & 63, w = t >> 6;
  const int lg = l >> 4, ll = l & 15;
  const int m0 = blockIdx.x * 128, n0 = blockIdx.y * 128;
  const int wm = (w >> 1) * 64, wn = (w & 1) * 64;

  f32x4 acc[4][4];
#pragma unroll
  for (int i = 0; i < 4; ++i)
#pragma unroll
    for (int j = 0; j < 4; ++j) acc[i][j] = (f32x4){0.f, 0.f, 0.f, 0.f};

  for (int k0 = 0; k0 < K; k0 += 32) {
    __syncthreads();
#pragma unroll
    for (int i = 0; i < 2; ++i) {
      u32 u = (u32)t * 16u + (u32)i * 4096u;
      u32 row = u >> 6, slot = (u >> 4) & 3u;
      u32 kb = (slot ^ ((row ^ (row >> 2)) & 3u)) * 8u;  // element offset of 16B slot
      async16(A + (size_t)(m0 + row) * K + k0 + kb, (char*)As + u);
      async16(BT + (size_t)(n0 + row) * K + k0 + kb, (char*)Bs + u);
    }
    asm volatile("s_waitcnt vmcnt(0)" ::: "memory");
    __syncthreads();

    s16x8 af[4], bfr[4];
#pragma unroll
    for (int mt = 0; mt < 4; ++mt) {
      u32 r = (u32)(wm + mt * 16 + ll);
      af[mt] = *(const s16x8*)((const char*)As + swz_byte(r, (u32)lg));
    }
#pragma unroll
    for (int nt = 0; nt < 4; ++nt) {
      u32 r = (u32)(wn + nt * 16 + ll);
      bfr[nt] = *(const s16x8*)((const char*)Bs + swz_byte(r, (u32)lg));
    }
#pragma unroll
    for (int mt = 0; mt < 4; ++mt)
#pragma unroll
      for (int nt = 0; nt < 4; ++nt)
        acc[mt][nt] = __builtin_amdgcn_mfma_f32_16x16x32_bf16(af[mt], bfr[nt], acc[mt][nt], 0, 0, 0);
  }

  if (MODE == 1) {
#pragma unroll
    for (int mt = 0; mt < 4; ++mt) {
      int srow = m0 + wm + mt * 16 + lg * 4;
#pragma unroll
      for (int nt = 0; nt < 4; ++nt) {
        int col = n0 + wn + nt * 16 + ll;
        f32x4 a = acc[mt][nt];
#pragma unroll
        for (int j = 0; j < 4; ++j) Cf[(size_t)(srow + j) * N + col] = a[j];
      }
    }
  } else {
#pragma unroll
    for (int nt = 0; nt < 4; ++nt) {
      int cb = n0 + wn + nt * 16;  // wave-uniform
#pragma unroll
      for (int mt = 0; mt < 4; ++mt) {
        int srow = m0 + wm + mt * 16 + lg * 4;
        f32x4 a = acc[mt][nt];
        if (cb < 2048) {
          int hh = cb >> 7, d = (cb & 127) + ll;
          u16* p = qr + ((size_t)hh * S_LEN) * HD + d;
#pragma unroll
          for (int j = 0; j < 4; ++j) p[(size_t)(srow + j) * HD] = f2bf(a[j]);
        } else if (cb < 2560) {
          int hh = (cb - 2048) >> 7, d = ((cb - 2048) & 127) + ll;
          u16* p = kr + ((size_t)hh * S_LEN) * HD + d;
#pragma unroll
          for (int j = 0; j < 4; ++j) p[(size_t)(srow + j) * HD] = f2bf(a[j]);
        } else {
          int hh = (cb - 2560) >> 7, d = ((cb - 2560) & 127) + ll;
          ushort4 pk;
          pk.x = f2bf(a[0]); pk.y = f2bf(a[1]); pk.z = f2bf(a[2]); pk.w = f2bf(a[3]);
          *(ushort4*)(vt + ((size_t)hh * HD + d) * S_LEN + srow) = pk;
        }
      }
    }
  }
}

// ---------------- attention ----------------
// Swapped-operand layout: mfma(K_frag, Q_frag) -> D[key_local][q]. Each lane owns
// q = ll (lane&15) and keys c + kt*16 + lg*4 + j  -> per-lane online softmax, no
// cross-lane ops in the chunk loop. Final 2-step butterfly merge over lg groups.
// grid (S/64, NH), block 256. Wave w handles q rows [qs, qs+16).
__global__ __launch_bounds__(256) void k_attn(const u16* __restrict__ qr, const u16* __restrict__ kr,
                                              const u16* __restrict__ vt, const float* __restrict__ lam,
                                              u16* __restrict__ ao) {
  __shared__ u16 P[4][16 * 40];  // per-wave P^T tile: [q=16][keys 32, stride 40]
  const int t = threadIdx.x;
  const int l = t & 63, w = t >> 6;
  const int lg = l >> 4, ll = l & 15;
  const int h = blockIdx.y;
  const int qs = blockIdx.x * 64 + w * 16;
  const int hk = h >> 2;
  const float lm = lam[h];
  const int row = qs + ll;  // this lane's q row

  const u16* Qp = qr + ((size_t)h * S_LEN + qs) * HD;
  const u16* Kp = kr + (size_t)hk * S_LEN * HD;
  const u16* Vp = vt + (size_t)hk * HD * S_LEN;

  // Q as B-fragment (pre-scaled by QSCALE in rope): lane holds Q[ll][i*32+lg*8 ..]
  s16x8 qa[4];
#pragma unroll
  for (int i = 0; i < 4; ++i)
    qa[i] = *(const s16x8*)(Qp + (size_t)ll * HD + i * 32 + lg * 8);

  int kbeg = qs - (WIN - 1);
  if (kbeg < 0) kbeg = 0;
  kbeg &= ~31;
  const int kend = qs + 15;

  const f32x4 zero = {0.f, 0.f, 0.f, 0.f};
  float m1 = -1e30f, z1 = 0.f, m2 = -1e30f, z2 = 0.f;

  // ---- pass 1: per-lane online softmax stats (exp2 domain) ----
  for (int c = kbeg; c <= kend; c += 32) {
    float s1v[8], s2v[8];
#pragma unroll
    for (int kt = 0; kt < 2; ++kt) {
      const u16* kp = Kp + (size_t)(c + kt * 16 + ll) * HD + lg * 8;
      s16x8 b0 = *(const s16x8*)(kp);
      s16x8 b1 = *(const s16x8*)(kp + 32);
      s16x8 b2 = *(const s16x8*)(kp + 64);
      s16x8 b3 = *(const s16x8*)(kp + 96);
      f32x4 a = __builtin_amdgcn_mfma_f32_16x16x32_bf16(b0, qa[0], zero, 0, 0, 0);
      a = __builtin_amdgcn_mfma_f32_16x16x32_bf16(b1, qa[1], a, 0, 0, 0);
      f32x4 b = __builtin_amdgcn_mfma_f32_16x16x32_bf16(b2, qa[2], zero, 0, 0, 0);
      b = __builtin_amdgcn_mfma_f32_16x16x32_bf16(b3, qa[3], b, 0, 0, 0);
#pragma unroll
      for (int j = 0; j < 4; ++j) { s1v[kt * 4 + j] = a[j]; s2v[kt * 4 + j] = b[j]; }
    }
    const bool full = (c + 31 <= qs) && (c >= qs - 496);  // wave-uniform
    if (!full) {
#pragma unroll
      for (int i = 0; i < 8; ++i) {
        int key = c + (i >> 2) * 16 + lg * 4 + (i & 3);
        bool ok = (key <= row) && (key > row - WIN);
        s1v[i] = ok ? s1v[i] : -1e30f;
        s2v[i] = ok ? s2v[i] : -1e30f;
      }
    }
    float cm1 = s1v[0], cm2 = s2v[0];
#pragma unroll
    for (int i = 1; i < 8; ++i) { cm1 = fmaxf(cm1, s1v[i]); cm2 = fmaxf(cm2, s2v[i]); }
    float nm1 = fmaxf(m1, cm1), nm2 = fmaxf(m2, cm2);
    float acc1 = 0.f, acc2 = 0.f;
    if (full) {
#pragma unroll
      for (int i = 0; i < 8; ++i) {
        acc1 += __builtin_amdgcn_exp2f(s1v[i] - nm1);
        acc2 += __builtin_amdgcn_exp2f(s2v[i] - nm2);
      }
    } else {
#pragma unroll
      for (int i = 0; i < 8; ++i) {
        acc1 += (s1v[i] > -1e29f) ? __builtin_amdgcn_exp2f(s1v[i] - nm1) : 0.f;
        acc2 += (s2v[i] > -1e29f) ? __builtin_amdgcn_exp2f(s2v[i] - nm2) : 0.f;
      }
    }
    z1 = z1 * __builtin_amdgcn_exp2f(m1 - nm1) + acc1;
    z2 = z2 * __builtin_amdgcn_exp2f(m2 - nm2) + acc2;
    m1 = nm1; m2 = nm2;
  }

  // merge the 4 lg-group partials (lanes ll, ll+16, ll+32, ll+48 share q=ll)
#pragma unroll
  for (int mk = 16; mk <= 32; mk <<= 1) {
    float om = __shfl_xor(m1, mk, 64), oz = __shfl_xor(z1, mk, 64);
    float nm = fmaxf(m1, om);
    z1 = z1 * __builtin_amdgcn_exp2f(m1 - nm) + oz * __builtin_amdgcn_exp2f(om - nm);
    m1 = nm;
    om = __shfl_xor(m2, mk, 64); oz = __shfl_xor(z2, mk, 64);
    nm = fmaxf(m2, om);
    z2 = z2 * __builtin_amdgcn_exp2f(m2 - nm) + oz * __builtin_amdgcn_exp2f(om - nm);
    m2 = nm;
  }
  const float rz1 = __builtin_amdgcn_rcpf(z1);
  const float rz2 = __builtin_amdgcn_rcpf(z2);

  // ---- pass 2: recompute scores, diff-combine, PV ----
  f32x4 o[8];
#pragma unroll
  for (int dt = 0; dt < 8; ++dt) o[dt] = zero;
  float dsum = 0.f;

  for (int c = kbeg; c <= kend; c += 32) {
    float s1v[8], s2v[8];
#pragma unroll
    for (int kt = 0; kt < 2; ++kt) {
      const u16* kp = Kp + (size_t)(c + kt * 16 + ll) * HD + lg * 8;
      s16x8 b0 = *(const s16x8*)(kp);
      s16x8 b1 = *(const s16x8*)(kp + 32);
      s16x8 b2 = *(const s16x8*)(kp + 64);
      s16x8 b3 = *(const s16x8*)(kp + 96);
      f32x4 a = __builtin_amdgcn_mfma_f32_16x16x32_bf16(b0, qa[0], zero, 0, 0, 0);
      a = __builtin_amdgcn_mfma_f32_16x16x32_bf16(b1, qa[1], a, 0, 0, 0);
      f32x4 b = __builtin_amdgcn_mfma_f32_16x16x32_bf16(b2, qa[2], zero, 0, 0, 0);
      b = __builtin_amdgcn_mfma_f32_16x16x32_bf16(b3, qa[3], b, 0, 0, 0);
#pragma unroll
      for (int j = 0; j < 4; ++j) { s1v[kt * 4 + j] = a[j]; s2v[kt * 4 + j] = b[j]; }
    }
    const bool full = (c + 31 <= qs) && (c >= qs - 496);
    if (!full) {
#pragma unroll
      for (int i = 0; i < 8; ++i) {
        int key = c + (i >> 2) * 16 + lg * 4 + (i & 3);
        bool ok = (key <= row) && (key > row - WIN);
        s1v[i] = ok ? s1v[i] : -1e30f;  // exp2(-1e30 - m) flushes to 0 (m finite here)
        s2v[i] = ok ? s2v[i] : -1e30f;
      }
    }
    float dv[8];
#pragma unroll
    for (int i = 0; i < 8; ++i) {
      float a1 = __builtin_amdgcn_exp2f(s1v[i] - m1) * rz1;
      float a2 = __builtin_amdgcn_exp2f(s2v[i] - m2) * rz2;
      float d = fmaxf(fmaf(-lm, a2, a1), 0.f);
      dv[i] = d;
      dsum += d;
    }
    ushort4 p0, p1;
    p0.x = f2bf(dv[0]); p0.y = f2bf(dv[1]); p0.z = f2bf(dv[2]); p0.w = f2bf(dv[3]);
    p1.x = f2bf(dv[4]); p1.y = f2bf(dv[5]); p1.z = f2bf(dv[6]); p1.w = f2bf(dv[7]);
    *(ushort4*)(&P[w][ll * 40 + lg * 4]) = p0;       // keys kt=0: lg*4..+3
    *(ushort4*)(&P[w][ll * 40 + 16 + lg * 4]) = p1;  // keys kt=1: 16+lg*4..+3
    // per-wave LDS transpose round-trip; compiler inserts lgkmcnt waits (may-alias).
    s16x8 pf = *(const s16x8*)(&P[w][ll * 40 + lg * 8]);
#pragma unroll
    for (int dt = 0; dt < 8; ++dt) {
      const u16* vp = Vp + (size_t)(dt * 16 + ll) * S_LEN + c + lg * 8;
      s16x8 vf = *(const s16x8*)vp;
      o[dt] = __builtin_amdgcn_mfma_f32_16x16x32_bf16(pf, vf, o[dt], 0, 0, 0);
    }
  }

  // dsum: merge lg partials, then fetch 1/(sum+eps) for output rows lg*4+j
  dsum += __shfl_xor(dsum, 16, 64);
  dsum += __shfl_xor(dsum, 32, 64);
  const float rds = __builtin_amdgcn_rcpf(dsum + 1e-6f);
  float rdsj[4];
#pragma unroll
  for (int j = 0; j < 4; ++j) rdsj[j] = __shfl(rds, lg * 4 + j, 64);

#pragma unroll
  for (int dt = 0; dt < 8; ++dt) {
#pragma unroll
    for (int j = 0; j < 4; ++j) {
      int srow = qs + lg * 4 + j;
      ao[(size_t)srow * DMODEL + h * HD + dt * 16 + ll] = f2bf(o[dt][j] * rdsj[j]);
    }
  }
}

// ---------------- launch ----------------

extern "C" void kernel_launch(void* const* d_in, const int* in_sizes, int n_in,
                              void* d_out, int out_size, void* d_ws, size_t ws_size,
                              hipStream_t stream) {
  const float* x = (const float*)d_in[0];
  const float* Wq = (const float*)d_in[1];
  const float* Wk = (const float*)d_in[2];
  const float* Wv = (const float*)d_in[3];
  const float* Wo = (const float*)d_in[4];
  const float* lam = (const float*)d_in[5];
  float* out = (float*)d_out;

  char* ws = (char*)d_ws;
  u16* xb = (u16*)(ws);                               // 8 MB  [2048][2048]
  u16* WT = (u16*)(ws + (8u << 20));                  // 12 MB [3072][2048] (Wq^T|Wk^T|Wv^T)
  u16* WoT = (u16*)(ws + (20u << 20));                // 8 MB  [2048][2048]
  u16* qr = (u16*)(ws + (28u << 20));                 // 8 MB  [16][2048][128]
  u16* kr = (u16*)(ws + (36u << 20));                 // 2 MB  [4][2048][128]
  u16* vt = (u16*)(ws + (38u << 20));                 // 2 MB  [4][128][2048]
  u16* ao = (u16*)(ws + (40u << 20));                 // 8 MB  [2048][2048]
  float2* cs = (float2*)(ws + (48u << 20));           // 1 MB  [2048][64]

  k_rope_table<<<S_LEN, 64, 0, stream>>>(cs);
  k_convert_bf16<<<4096, 256, 0, stream>>>(x, xb, (S_LEN * DMODEL) / 4);

  dim3 tb(32, 8);
  k_transpose_bf16<<<dim3(2048 / 32, 2048 / 32), tb, 0, stream>>>(Wq, WT, 2048, 2048);
  k_transpose_bf16<<<dim3(512 / 32, 2048 / 32), tb, 0, stream>>>(Wk, WT + (size_t)2048 * 2048, 2048, 512);
  k_transpose_bf16<<<dim3(512 / 32, 2048 / 32), tb, 0, stream>>>(Wv, WT + (size_t)2560 * 2048, 2048, 512);
  k_transpose_bf16<<<dim3(2048 / 32, 2048 / 32), tb, 0, stream>>>(Wo, WoT, 2048, 2048);

  k_gemm<0><<<dim3(16, 24), 256, 0, stream>>>(xb, WT, nullptr, 2048, 3072, qr, kr, vt);

  // Q pre-scaled by 0.125*log2(e) -> QK^T scores land directly in exp2 domain
  k_rope_apply<<<(NH * S_LEN * 64) / 256, 256, 0, stream>>>(qr, cs, NH * S_LEN, QSCALE);
  k_rope_apply<<<(NKV * S_LEN * 64) / 256, 256, 0, stream>>>(kr, cs, NKV * S_LEN, 1.0f);

  k_attn<<<dim3(S_LEN / 64, NH), 256, 0, stream>>>(qr, kr, vt, lam, ao);

  k_gemm<1><<<dim3(16, 16), 256, 0, stream>>>(ao, WoT, out, 2048, 2048, nullptr, nullptr, nullptr);
}

// Round 3
// 182.189 us; speedup vs baseline: 1.3202x; 1.2698x over previous
//
#include <hip/hip_runtime.h>

typedef unsigned int u32;
typedef unsigned short u16;
typedef __attribute__((ext_vector_type(4))) float f32x4;
typedef __attribute__((ext_vector_type(8))) short s16x8;

#define S_LEN 2048
#define DMODEL 2048
#define NH 16
#define NKV 4
#define HD 128
#define WIN 512
// 0.125 (1/sqrt(64)) * log2(e): folds score scale + exp2-domain conversion into Q
#define QSCALE 0.18033688011112042f

__device__ __forceinline__ u16 f2bf(float f) {
  union { float f; u32 u; } v; v.f = f;
  u32 r = v.u + 0x7FFFu + ((v.u >> 16) & 1u);
  return (u16)(r >> 16);
}
__device__ __forceinline__ float bf2f(u16 h) {
  union { u32 u; float f; } v; v.u = ((u32)h) << 16;
  return v.f;
}

__device__ __forceinline__ void async16(const void* g, void* l) {
  __builtin_amdgcn_global_load_lds((const __attribute__((address_space(1))) void*)g,
                                   (__attribute__((address_space(3))) void*)l, 16, 0, 0);
}

// ---------------- prep kernels ----------------

__global__ void k_rope_table(float2* __restrict__ cs) {
  int s = blockIdx.x, d = threadIdx.x;  // d in [0,64)
  float invf = expf(-((float)(2 * d) / (float)HD) * logf(10000.0f));
  float fr = (float)s * invf;
  float sv, cv;
  sincosf(fr, &sv, &cv);
  cs[s * 64 + d] = make_float2(cv, sv);
}

__global__ void k_convert_bf16(const float* __restrict__ src, u16* __restrict__ dst, int n4) {
  int i = blockIdx.x * blockDim.x + threadIdx.x;
  if (i >= n4) return;
  float4 v = ((const float4*)src)[i];
  ushort4 o;
  o.x = f2bf(v.x); o.y = f2bf(v.y); o.z = f2bf(v.z); o.w = f2bf(v.w);
  ((ushort4*)dst)[i] = o;
}

// dst[n*K + k] = bf16(src[k*N + n]);  grid=(N/32, K/32), block=(32,8)
__global__ __launch_bounds__(256) void k_transpose_bf16(const float* __restrict__ src,
                                                        u16* __restrict__ dst, int K, int N) {
  __shared__ float tile[32][33];
  int tx = threadIdx.x, ty = threadIdx.y;
  int n0 = blockIdx.x * 32, k0 = blockIdx.y * 32;
#pragma unroll
  for (int i = 0; i < 4; ++i)
    tile[ty + 8 * i][tx] = src[(size_t)(k0 + ty + 8 * i) * N + n0 + tx];
  __syncthreads();
#pragma unroll
  for (int i = 0; i < 4; ++i)
    dst[(size_t)(n0 + ty + 8 * i) * K + k0 + tx] = f2bf(tile[tx][ty + 8 * i]);
}

// rope in-place on [nrows][128] bf16, row s = row & (S_LEN-1); optional uniform scale.
__global__ void k_rope_apply(u16* __restrict__ q, const float2* __restrict__ cs, int nrows,
                             float scale) {
  int i = blockIdx.x * blockDim.x + threadIdx.x;
  if (i >= nrows * 64) return;
  int row = i >> 6, d = i & 63;
  int s = row & (S_LEN - 1);
  float2 c = cs[s * 64 + d];
  u16* p = q + (size_t)row * HD;
  float a = bf2f(p[d]), b = bf2f(p[d + 64]);
  p[d]      = f2bf((a * c.x - b * c.y) * scale);
  p[d + 64] = f2bf((b * c.x + a * c.y) * scale);
}

// ---------------- GEMM ----------------
// A [M][K] bf16 row-major, BT [N][K] bf16. 128x128 tile, BK=32, 4 waves (2x2 of 64x64).
// MODE 0: scatter epilogue -> qr[h][s][d], kr[h][s][d], vt[h][d][s]
// MODE 1: plain fp32 C[M][N]

__device__ __forceinline__ u32 swz_byte(u32 row, u32 slot) {
  return row * 64u + ((slot ^ ((row ^ (row >> 2)) & 3u)) * 16u);
}

template <int MODE>
__global__ __launch_bounds__(256) void k_gemm(const u16* __restrict__ A, const u16* __restrict__ BT,
                                              float* __restrict__ Cf, int K, int N,
                                              u16* __restrict__ qr, u16* __restrict__ kr,
                                              u16* __restrict__ vt) {
  __shared__ u16 As[128 * 32];
  __shared__ u16 Bs[128 * 32];
  const int t = threadIdx.x;
  const int l = t & 63, w = t >> 6;
  const int lg = l >> 4, ll = l & 15;
  const int m0 = blockIdx.x * 128, n0 = blockIdx.y * 128;
  const int wm = (w >> 1) * 64, wn = (w & 1) * 64;

  f32x4 acc[4][4];
#pragma unroll
  for (int i = 0; i < 4; ++i)
#pragma unroll
    for (int j = 0; j < 4; ++j) acc[i][j] = (f32x4){0.f, 0.f, 0.f, 0.f};

  for (int k0 = 0; k0 < K; k0 += 32) {
    __syncthreads();
#pragma unroll
    for (int i = 0; i < 2; ++i) {
      u32 u = (u32)t * 16u + (u32)i * 4096u;
      u32 row = u >> 6, slot = (u >> 4) & 3u;
      u32 kb = (slot ^ ((row ^ (row >> 2)) & 3u)) * 8u;  // element offset of 16B slot
      async16(A + (size_t)(m0 + row) * K + k0 + kb, (char*)As + u);
      async16(BT + (size_t)(n0 + row) * K + k0 + kb, (char*)Bs + u);
    }
    asm volatile("s_waitcnt vmcnt(0)" ::: "memory");
    __syncthreads();

    s16x8 af[4], bfr[4];
#pragma unroll
    for (int mt = 0; mt < 4; ++mt) {
      u32 r = (u32)(wm + mt * 16 + ll);
      af[mt] = *(const s16x8*)((const char*)As + swz_byte(r, (u32)lg));
    }
#pragma unroll
    for (int nt = 0; nt < 4; ++nt) {
      u32 r = (u32)(wn + nt * 16 + ll);
      bfr[nt] = *(const s16x8*)((const char*)Bs + swz_byte(r, (u32)lg));
    }
#pragma unroll
    for (int mt = 0; mt < 4; ++mt)
#pragma unroll
      for (int nt = 0; nt < 4; ++nt)
        acc[mt][nt] = __builtin_amdgcn_mfma_f32_16x16x32_bf16(af[mt], bfr[nt], acc[mt][nt], 0, 0, 0);
  }

  if (MODE == 1) {
#pragma unroll
    for (int mt = 0; mt < 4; ++mt) {
      int srow = m0 + wm + mt * 16 + lg * 4;
#pragma unroll
      for (int nt = 0; nt < 4; ++nt) {
        int col = n0 + wn + nt * 16 + ll;
        f32x4 a = acc[mt][nt];
#pragma unroll
        for (int j = 0; j < 4; ++j) Cf[(size_t)(srow + j) * N + col] = a[j];
      }
    }
  } else {
#pragma unroll
    for (int nt = 0; nt < 4; ++nt) {
      int cb = n0 + wn + nt * 16;  // wave-uniform
#pragma unroll
      for (int mt = 0; mt < 4; ++mt) {
        int srow = m0 + wm + mt * 16 + lg * 4;
        f32x4 a = acc[mt][nt];
        if (cb < 2048) {
          int hh = cb >> 7, d = (cb & 127) + ll;
          u16* p = qr + ((size_t)hh * S_LEN) * HD + d;
#pragma unroll
          for (int j = 0; j < 4; ++j) p[(size_t)(srow + j) * HD] = f2bf(a[j]);
        } else if (cb < 2560) {
          int hh = (cb - 2048) >> 7, d = ((cb - 2048) & 127) + ll;
          u16* p = kr + ((size_t)hh * S_LEN) * HD + d;
#pragma unroll
          for (int j = 0; j < 4; ++j) p[(size_t)(srow + j) * HD] = f2bf(a[j]);
        } else {
          int hh = (cb - 2560) >> 7, d = ((cb - 2560) & 127) + ll;
          ushort4 pk;
          pk.x = f2bf(a[0]); pk.y = f2bf(a[1]); pk.z = f2bf(a[2]); pk.w = f2bf(a[3]);
          *(ushort4*)(vt + ((size_t)hh * HD + d) * S_LEN + srow) = pk;
        }
      }
    }
  }
}

// ---------------- attention ----------------
// Block-cooperative, double-buffered LDS staging (T3 2-phase). Block = 64 q rows
// x 1 head, 4 waves; all 4 waves share one chunk stream over the block's key
// union [kbeg, bq+63]. K staged [32 rows][256B] slot^=(row&7); V staged packed
// [64 r][128B] (2 d-rows per LDS row) slot^=(r&7). Both via global_load_lds with
// inverse-swizzled GLOBAL source + linear LDS dest (+ swizzled read) per rule 21.
// Per-lane online softmax (swapped QK^T) as before.
__global__ __launch_bounds__(256) void k_attn(const u16* __restrict__ qr, const u16* __restrict__ kr,
                                              const u16* __restrict__ vt, const float* __restrict__ lam,
                                              u16* __restrict__ ao) {
  __shared__ u16 Ks[2][32 * 128];  // 2 x 8KB
  __shared__ u16 Vs[2][64 * 64];   // 2 x 8KB (paired-row: LDS row r holds d=2r,2r+1)
  __shared__ u16 P[4][16 * 40];    // per-wave P^T transpose tile
  const int t = threadIdx.x;
  const int l = t & 63, w = t >> 6;
  const int lg = l >> 4, ll = l & 15;
  const int h = blockIdx.y;
  const int bq = blockIdx.x * 64;
  const int qs = bq + w * 16;
  const int hk = h >> 2;
  const float lm = lam[h];
  const int row = qs + ll;  // this lane's q row

  const u16* Qp = qr + ((size_t)h * S_LEN + qs) * HD;
  const u16* Kp = kr + (size_t)hk * S_LEN * HD;
  const u16* Vp = vt + (size_t)hk * HD * S_LEN;

  // block-union chunk range
  int kbeg = bq - (WIN - 1);
  if (kbeg < 0) kbeg = 0;
  kbeg &= ~31;
  const int nch = (bq + 63 - kbeg + 32) / 32;

  // staging coordinates (computed once; c varies)
  // K: thread t, issue j covers LDS bytes u=t*16+j*4096 of an 8KB buffer
  u32 ku[2], krow[2], kslot[2];
#pragma unroll
  for (int j = 0; j < 2; ++j) {
    u32 u = (u32)t * 16u + (u32)j * 4096u;
    ku[j] = u;
    krow[j] = u >> 8;                        // 0..31
    kslot[j] = ((u >> 4) & 15u) ^ (krow[j] & 7u);  // inverse-swizzled 16B slot
  }
  // V: LDS row r=u>>7 (128B rows), phys slot (u>>4)&7 -> logical slot -> (d, k0)
  u32 vd[2], vk0[2];
#pragma unroll
  for (int j = 0; j < 2; ++j) {
    u32 u = ku[j];
    u32 r = u >> 7;                          // 0..63
    u32 sl = ((u >> 4) & 7u) ^ (r & 7u);     // logical slot 0..7
    vd[j] = r * 2 + (sl >> 2);               // d row 0..127
    vk0[j] = (sl & 3u) * 8u;                 // key element offset 0..24
  }

  // Q as B-fragment (pre-scaled by QSCALE in rope)
  s16x8 qa[4];
#pragma unroll
  for (int i = 0; i < 4; ++i)
    qa[i] = *(const s16x8*)(Qp + (size_t)ll * HD + i * 32 + lg * 8);

  const f32x4 zero = {0.f, 0.f, 0.f, 0.f};
  float m1 = -1e30f, z1 = 0.f, m2 = -1e30f, z2 = 0.f;

  // ---- pass 1: per-lane online softmax stats (K staged, dbuf) ----
#pragma unroll
  for (int j = 0; j < 2; ++j)
    async16(Kp + (size_t)(kbeg + krow[j]) * HD + kslot[j] * 8, (char*)Ks[0] + ku[j]);
  __syncthreads();

  for (int tc = 0; tc < nch; ++tc) {
    const int c = kbeg + tc * 32;
    if (tc + 1 < nch) {
      const int cn = c + 32;
#pragma unroll
      for (int j = 0; j < 2; ++j)
        async16(Kp + (size_t)(cn + krow[j]) * HD + kslot[j] * 8, (char*)Ks[(tc + 1) & 1] + ku[j]);
    }
    const bool active = (c + 31 >= qs - (WIN - 1)) && (c <= qs + 15);
    if (active) {
      const u16* Kb = Ks[tc & 1];
      float s1v[8], s2v[8];
#pragma unroll
      for (int kt = 0; kt < 2; ++kt) {
        const int kr_ = kt * 16 + ll;
        const u16* kp = Kb + kr_ * 128;
        const u32 sw = (u32)(kr_ & 7);
        s16x8 b0 = *(const s16x8*)(kp + ((lg ^ sw) * 8));
        s16x8 b1 = *(const s16x8*)(kp + (((4 + lg) ^ sw) * 8));
        s16x8 b2 = *(const s16x8*)(kp + (((8 + lg) ^ sw) * 8));
        s16x8 b3 = *(const s16x8*)(kp + (((12 + lg) ^ sw) * 8));
        f32x4 a = __builtin_amdgcn_mfma_f32_16x16x32_bf16(b0, qa[0], zero, 0, 0, 0);
        a = __builtin_amdgcn_mfma_f32_16x16x32_bf16(b1, qa[1], a, 0, 0, 0);
        f32x4 b = __builtin_amdgcn_mfma_f32_16x16x32_bf16(b2, qa[2], zero, 0, 0, 0);
        b = __builtin_amdgcn_mfma_f32_16x16x32_bf16(b3, qa[3], b, 0, 0, 0);
#pragma unroll
        for (int j = 0; j < 4; ++j) { s1v[kt * 4 + j] = a[j]; s2v[kt * 4 + j] = b[j]; }
      }
      const bool full = (c + 31 <= qs) && (c >= qs - 496);  // wave-uniform
      if (!full) {
#pragma unroll
        for (int i = 0; i < 8; ++i) {
          int key = c + (i >> 2) * 16 + lg * 4 + (i & 3);
          bool ok = (key <= row) && (key > row - WIN);
          s1v[i] = ok ? s1v[i] : -1e30f;
          s2v[i] = ok ? s2v[i] : -1e30f;
        }
      }
      float cm1 = s1v[0], cm2 = s2v[0];
#pragma unroll
      for (int i = 1; i < 8; ++i) { cm1 = fmaxf(cm1, s1v[i]); cm2 = fmaxf(cm2, s2v[i]); }
      float nm1 = fmaxf(m1, cm1), nm2 = fmaxf(m2, cm2);
      float acc1 = 0.f, acc2 = 0.f;
      if (full) {
#pragma unroll
        for (int i = 0; i < 8; ++i) {
          acc1 += __builtin_amdgcn_exp2f(s1v[i] - nm1);
          acc2 += __builtin_amdgcn_exp2f(s2v[i] - nm2);
        }
      } else {
#pragma unroll
        for (int i = 0; i < 8; ++i) {
          acc1 += (s1v[i] > -1e29f) ? __builtin_amdgcn_exp2f(s1v[i] - nm1) : 0.f;
          acc2 += (s2v[i] > -1e29f) ? __builtin_amdgcn_exp2f(s2v[i] - nm2) : 0.f;
        }
      }
      z1 = z1 * __builtin_amdgcn_exp2f(m1 - nm1) + acc1;
      z2 = z2 * __builtin_amdgcn_exp2f(m2 - nm2) + acc2;
      m1 = nm1; m2 = nm2;
    }
    __syncthreads();
  }

  // merge the 4 lg-group partials (lanes ll, ll+16, ll+32, ll+48 share q=ll)
#pragma unroll
  for (int mk = 16; mk <= 32; mk <<= 1) {
    float om = __shfl_xor(m1, mk, 64), oz = __shfl_xor(z1, mk, 64);
    float nm = fmaxf(m1, om);
    z1 = z1 * __builtin_amdgcn_exp2f(m1 - nm) + oz * __builtin_amdgcn_exp2f(om - nm);
    m1 = nm;
    om = __shfl_xor(m2, mk, 64); oz = __shfl_xor(z2, mk, 64);
    nm = fmaxf(m2, om);
    z2 = z2 * __builtin_amdgcn_exp2f(m2 - nm) + oz * __builtin_amdgcn_exp2f(om - nm);
    m2 = nm;
  }
  const float rz1 = __builtin_amdgcn_rcpf(z1);
  const float rz2 = __builtin_amdgcn_rcpf(z2);

  // ---- pass 2: recompute scores, diff-combine, PV (K+V staged, dbuf) ----
  f32x4 o[8];
#pragma unroll
  for (int dt = 0; dt < 8; ++dt) o[dt] = zero;
  float dsum = 0.f;

#pragma unroll
  for (int j = 0; j < 2; ++j) {
    async16(Kp + (size_t)(kbeg + krow[j]) * HD + kslot[j] * 8, (char*)Ks[0] + ku[j]);
    async16(Vp + (size_t)vd[j] * S_LEN + kbeg + vk0[j], (char*)Vs[0] + ku[j]);
  }
  __syncthreads();

  for (int tc = 0; tc < nch; ++tc) {
    const int c = kbeg + tc * 32;
    if (tc + 1 < nch) {
      const int cn = c + 32;
#pragma unroll
      for (int j = 0; j < 2; ++j) {
        async16(Kp + (size_t)(cn + krow[j]) * HD + kslot[j] * 8, (char*)Ks[(tc + 1) & 1] + ku[j]);
        async16(Vp + (size_t)vd[j] * S_LEN + cn + vk0[j], (char*)Vs[(tc + 1) & 1] + ku[j]);
      }
    }
    const bool active = (c + 31 >= qs - (WIN - 1)) && (c <= qs + 15);
    if (active) {
      const u16* Kb = Ks[tc & 1];
      const u16* Vb = Vs[tc & 1];
      float s1v[8], s2v[8];
#pragma unroll
      for (int kt = 0; kt < 2; ++kt) {
        const int kr_ = kt * 16 + ll;
        const u16* kp = Kb + kr_ * 128;
        const u32 sw = (u32)(kr_ & 7);
        s16x8 b0 = *(const s16x8*)(kp + ((lg ^ sw) * 8));
        s16x8 b1 = *(const s16x8*)(kp + (((4 + lg) ^ sw) * 8));
        s16x8 b2 = *(const s16x8*)(kp + (((8 + lg) ^ sw) * 8));
        s16x8 b3 = *(const s16x8*)(kp + (((12 + lg) ^ sw) * 8));
        f32x4 a = __builtin_amdgcn_mfma_f32_16x16x32_bf16(b0, qa[0], zero, 0, 0, 0);
        a = __builtin_amdgcn_mfma_f32_16x16x32_bf16(b1, qa[1], a, 0, 0, 0);
        f32x4 b = __builtin_amdgcn_mfma_f32_16x16x32_bf16(b2, qa[2], zero, 0, 0, 0);
        b = __builtin_amdgcn_mfma_f32_16x16x32_bf16(b3, qa[3], b, 0, 0, 0);
#pragma unroll
        for (int j = 0; j < 4; ++j) { s1v[kt * 4 + j] = a[j]; s2v[kt * 4 + j] = b[j]; }
      }
      const bool full = (c + 31 <= qs) && (c >= qs - 496);
      if (!full) {
#pragma unroll
        for (int i = 0; i < 8; ++i) {
          int key = c + (i >> 2) * 16 + lg * 4 + (i & 3);
          bool ok = (key <= row) && (key > row - WIN);
          s1v[i] = ok ? s1v[i] : -1e30f;
          s2v[i] = ok ? s2v[i] : -1e30f;
        }
      }
      float dv[8];
#pragma unroll
      for (int i = 0; i < 8; ++i) {
        float a1 = __builtin_amdgcn_exp2f(s1v[i] - m1) * rz1;
        float a2 = __builtin_amdgcn_exp2f(s2v[i] - m2) * rz2;
        float d = fmaxf(fmaf(-lm, a2, a1), 0.f);
        dv[i] = d;
        dsum += d;
      }
      ushort4 p0, p1;
      p0.x = f2bf(dv[0]); p0.y = f2bf(dv[1]); p0.z = f2bf(dv[2]); p0.w = f2bf(dv[3]);
      p1.x = f2bf(dv[4]); p1.y = f2bf(dv[5]); p1.z = f2bf(dv[6]); p1.w = f2bf(dv[7]);
      *(ushort4*)(&P[w][ll * 40 + lg * 4]) = p0;       // keys kt=0: lg*4..+3
      *(ushort4*)(&P[w][ll * 40 + 16 + lg * 4]) = p1;  // keys kt=1: 16+lg*4..+3
      s16x8 pf = *(const s16x8*)(&P[w][ll * 40 + lg * 8]);
#pragma unroll
      for (int dt = 0; dt < 8; ++dt) {
        const int d = dt * 16 + ll;
        const u32 r = (u32)(d >> 1);
        const u32 sl = (u32)(((d & 1) * 4 + lg)) ^ (r & 7u);
        s16x8 vf = *(const s16x8*)(Vb + r * 64 + sl * 8);
        o[dt] = __builtin_amdgcn_mfma_f32_16x16x32_bf16(pf, vf, o[dt], 0, 0, 0);
      }
    }
    __syncthreads();
  }

  // dsum: merge lg partials, then fetch 1/(sum+eps) for output rows lg*4+j
  dsum += __shfl_xor(dsum, 16, 64);
  dsum += __shfl_xor(dsum, 32, 64);
  const float rds = __builtin_amdgcn_rcpf(dsum + 1e-6f);
  float rdsj[4];
#pragma unroll
  for (int j = 0; j < 4; ++j) rdsj[j] = __shfl(rds, lg * 4 + j, 64);

#pragma unroll
  for (int dt = 0; dt < 8; ++dt) {
#pragma unroll
    for (int j = 0; j < 4; ++j) {
      int srow = qs + lg * 4 + j;
      ao[(size_t)srow * DMODEL + h * HD + dt * 16 + ll] = f2bf(o[dt][j] * rdsj[j]);
    }
  }
}

// ---------------- launch ----------------

extern "C" void kernel_launch(void* const* d_in, const int* in_sizes, int n_in,
                              void* d_out, int out_size, void* d_ws, size_t ws_size,
                              hipStream_t stream) {
  const float* x = (const float*)d_in[0];
  const float* Wq = (const float*)d_in[1];
  const float* Wk = (const float*)d_in[2];
  const float* Wv = (const float*)d_in[3];
  const float* Wo = (const float*)d_in[4];
  const float* lam = (const float*)d_in[5];
  float* out = (float*)d_out;

  char* ws = (char*)d_ws;
  u16* xb = (u16*)(ws);                               // 8 MB  [2048][2048]
  u16* WT = (u16*)(ws + (8u << 20));                  // 12 MB [3072][2048] (Wq^T|Wk^T|Wv^T)
  u16* WoT = (u16*)(ws + (20u << 20));                // 8 MB  [2048][2048]
  u16* qr = (u16*)(ws + (28u << 20));                 // 8 MB  [16][2048][128]
  u16* kr = (u16*)(ws + (36u << 20));                 // 2 MB  [4][2048][128]
  u16* vt = (u16*)(ws + (38u << 20));                 // 2 MB  [4][128][2048]
  u16* ao = (u16*)(ws + (40u << 20));                 // 8 MB  [2048][2048]
  float2* cs = (float2*)(ws + (48u << 20));           // 1 MB  [2048][64]

  k_rope_table<<<S_LEN, 64, 0, stream>>>(cs);
  k_convert_bf16<<<4096, 256, 0, stream>>>(x, xb, (S_LEN * DMODEL) / 4);

  dim3 tb(32, 8);
  k_transpose_bf16<<<dim3(2048 / 32, 2048 / 32), tb, 0, stream>>>(Wq, WT, 2048, 2048);
  k_transpose_bf16<<<dim3(512 / 32, 2048 / 32), tb, 0, stream>>>(Wk, WT + (size_t)2048 * 2048, 2048, 512);
  k_transpose_bf16<<<dim3(512 / 32, 2048 / 32), tb, 0, stream>>>(Wv, WT + (size_t)2560 * 2048, 2048, 512);
  k_transpose_bf16<<<dim3(2048 / 32, 2048 / 32), tb, 0, stream>>>(Wo, WoT, 2048, 2048);

  k_gemm<0><<<dim3(16, 24), 256, 0, stream>>>(xb, WT, nullptr, 2048, 3072, qr, kr, vt);

  // Q pre-scaled by 0.125*log2(e) -> QK^T scores land directly in exp2 domain
  k_rope_apply<<<(NH * S_LEN * 64) / 256, 256, 0, stream>>>(qr, cs, NH * S_LEN, QSCALE);
  k_rope_apply<<<(NKV * S_LEN * 64) / 256, 256, 0, stream>>>(kr, cs, NKV * S_LEN, 1.0f);

  k_attn<<<dim3(S_LEN / 64, NH), 256, 0, stream>>>(qr, kr, vt, lam, ao);

  k_gemm<1><<<dim3(16, 16), 256, 0, stream>>>(ao, WoT, out, 2048, 2048, nullptr, nullptr, nullptr);
}

// Round 4
// 155.899 us; speedup vs baseline: 1.5429x; 1.1686x over previous
//
#include <hip/hip_runtime.h>

typedef unsigned int u32;
typedef unsigned short u16;
typedef __attribute__((ext_vector_type(4))) float f32x4;
typedef __attribute__((ext_vector_type(8))) short s16x8;

#define S_LEN 2048
#define DMODEL 2048
#define NH 16
#define NKV 4
#define HD 128
#define WIN 512
// 0.125 (1/sqrt(64)) * log2(e): folds score scale + exp2-domain conversion into Q
#define QSCALE 0.18033688011112042f

__device__ __forceinline__ u16 f2bf(float f) {
  union { float f; u32 u; } v; v.f = f;
  u32 r = v.u + 0x7FFFu + ((v.u >> 16) & 1u);
  return (u16)(r >> 16);
}
__device__ __forceinline__ float bf2f(u16 h) {
  union { u32 u; float f; } v; v.u = ((u32)h) << 16;
  return v.f;
}

__device__ __forceinline__ void async16(const void* g, void* l) {
  __builtin_amdgcn_global_load_lds((const __attribute__((address_space(1))) void*)g,
                                   (__attribute__((address_space(3))) void*)l, 16, 0, 0);
}

// ---------------- prep kernels ----------------

__global__ void k_rope_table(float2* __restrict__ cs) {
  int s = blockIdx.x, d = threadIdx.x;  // d in [0,64)
  float invf = expf(-((float)(2 * d) / (float)HD) * logf(10000.0f));
  float fr = (float)s * invf;
  float sv, cv;
  sincosf(fr, &sv, &cv);
  cs[s * 64 + d] = make_float2(cv, sv);
}

__global__ void k_convert_bf16(const float* __restrict__ src, u16* __restrict__ dst, int n4) {
  int i = blockIdx.x * blockDim.x + threadIdx.x;
  if (i >= n4) return;
  float4 v = ((const float4*)src)[i];
  ushort4 o;
  o.x = f2bf(v.x); o.y = f2bf(v.y); o.z = f2bf(v.z); o.w = f2bf(v.w);
  ((ushort4*)dst)[i] = o;
}

// dst[n*K + k] = bf16(src[k*N + n]);  grid=(N/32, K/32), block=(32,8)
__global__ __launch_bounds__(256) void k_transpose_bf16(const float* __restrict__ src,
                                                        u16* __restrict__ dst, int K, int N) {
  __shared__ float tile[32][33];
  int tx = threadIdx.x, ty = threadIdx.y;
  int n0 = blockIdx.x * 32, k0 = blockIdx.y * 32;
#pragma unroll
  for (int i = 0; i < 4; ++i)
    tile[ty + 8 * i][tx] = src[(size_t)(k0 + ty + 8 * i) * N + n0 + tx];
  __syncthreads();
#pragma unroll
  for (int i = 0; i < 4; ++i)
    dst[(size_t)(n0 + ty + 8 * i) * K + k0 + tx] = f2bf(tile[tx][ty + 8 * i]);
}

// rope in-place on [nrows][128] bf16, row s = row & (S_LEN-1); optional uniform scale.
__global__ void k_rope_apply(u16* __restrict__ q, const float2* __restrict__ cs, int nrows,
                             float scale) {
  int i = blockIdx.x * blockDim.x + threadIdx.x;
  if (i >= nrows * 64) return;
  int row = i >> 6, d = i & 63;
  int s = row & (S_LEN - 1);
  float2 c = cs[s * 64 + d];
  u16* p = q + (size_t)row * HD;
  float a = bf2f(p[d]), b = bf2f(p[d + 64]);
  p[d]      = f2bf((a * c.x - b * c.y) * scale);
  p[d + 64] = f2bf((b * c.x + a * c.y) * scale);
}

// ---------------- GEMM ----------------
// A [M][K] bf16 row-major, BT [N][K] bf16. 64x128 tile, BK=32, 4 waves (2x2 of
// 32x64), double-buffered LDS (T3 2-phase: stage t+1 before compute t, one
// barrier per K-step), chunked XCD swizzle (m-fastest => B-panel stays hot in
// the XCD's private L2).
// MODE 0: scatter epilogue -> qr[h][s][d], kr[h][s][d], vt[h][d][s]
// MODE 1: plain fp32 C[M][N]

template <int MODE>
__global__ __launch_bounds__(256) void k_gemm(const u16* __restrict__ A, const u16* __restrict__ BT,
                                              float* __restrict__ Cf, int K, int N,
                                              u16* __restrict__ qr, u16* __restrict__ kr,
                                              u16* __restrict__ vt) {
  // combined A(64 rows)+B(128 rows) tile, row = 32 u16 = 64B, 12KB per buffer
  __shared__ u16 S[2][192 * 32];
  const int t = threadIdx.x;
  const int l = t & 63, w = t >> 6;
  const int lg = l >> 4, ll = l & 15;

  // chunked XCD swizzle (bijective: nwg % 8 == 0 for both call sites)
  const u32 nwg = gridDim.x * gridDim.y;
  const u32 bid = blockIdx.y * gridDim.x + blockIdx.x;  // m-fastest linearization
  const u32 sid = (bid & 7u) * (nwg >> 3) + (bid >> 3);
  const int m0 = (int)(sid % gridDim.x) * 64;
  const int n0 = (int)(sid / gridDim.x) * 128;

  const int wm = (w >> 1) * 32, wn = (w & 1) * 64;

  // staging coords: thread t, issue j covers LDS bytes u = t*16 + j*4096.
  // j=0 -> A rows 0..63; j=1,2 -> B rows 0..127. Inverse-swizzled global source
  // (rule 21): 16B slot kb = (slot ^ f(row)) where f(r) = (r ^ r>>2) & 3.
  const u16* gp[3];
  u32 lo[3];
#pragma unroll
  for (int j = 0; j < 3; ++j) {
    u32 u = (u32)t * 16u + (u32)j * 4096u;
    u32 row = u >> 6;
    u32 slot = (u >> 4) & 3u;
    u32 kb = (slot ^ ((row ^ (row >> 2)) & 3u)) * 8u;
    lo[j] = u;
    gp[j] = (j == 0 ? A + (size_t)(m0 + (int)row) * K
                    : BT + (size_t)(n0 + (int)(row - 64)) * K) + kb;
  }
  auto stage = [&](int b, int k0) {
#pragma unroll
    for (int j = 0; j < 3; ++j) async16(gp[j] + k0, (char*)S[b] + lo[j]);
  };

  f32x4 acc[2][4];
#pragma unroll
  for (int i = 0; i < 2; ++i)
#pragma unroll
    for (int j = 0; j < 4; ++j) acc[i][j] = (f32x4){0.f, 0.f, 0.f, 0.f};

  stage(0, 0);
  __syncthreads();  // compiler drains vmcnt(0) before barrier

  const int nit = K / 32;
#pragma unroll 2
  for (int it = 0; it < nit; ++it) {
    const int cur = it & 1;
    if (it + 1 < nit) stage(cur ^ 1, (it + 1) * 32);  // prefetch overlaps compute below

    s16x8 af[2], bq[4];
#pragma unroll
    for (int mt = 0; mt < 2; ++mt) {
      u32 r = (u32)(wm + mt * 16 + ll);
      af[mt] = *(const s16x8*)((const char*)S[cur] + r * 64u +
                               ((lg ^ ((r ^ (r >> 2)) & 3u)) * 16u));
    }
#pragma unroll
    for (int nt = 0; nt < 4; ++nt) {
      u32 r = (u32)(wn + nt * 16 + ll);
      bq[nt] = *(const s16x8*)((const char*)S[cur] + 4096u + r * 64u +
                               ((lg ^ ((r ^ (r >> 2)) & 3u)) * 16u));
    }
#pragma unroll
    for (int mt = 0; mt < 2; ++mt)
#pragma unroll
      for (int nt = 0; nt < 4; ++nt)
        acc[mt][nt] = __builtin_amdgcn_mfma_f32_16x16x32_bf16(af[mt], bq[nt], acc[mt][nt], 0, 0, 0);
    __syncthreads();  // drains staged loads (vmcnt 0) + protects buffer reuse
  }

  if (MODE == 1) {
#pragma unroll
    for (int mt = 0; mt < 2; ++mt) {
      int srow = m0 + wm + mt * 16 + lg * 4;
#pragma unroll
      for (int nt = 0; nt < 4; ++nt) {
        int col = n0 + wn + nt * 16 + ll;
        f32x4 a = acc[mt][nt];
#pragma unroll
        for (int j = 0; j < 4; ++j) Cf[(size_t)(srow + j) * N + col] = a[j];
      }
    }
  } else {
#pragma unroll
    for (int nt = 0; nt < 4; ++nt) {
      int cb = n0 + wn + nt * 16;  // wave-uniform
#pragma unroll
      for (int mt = 0; mt < 2; ++mt) {
        int srow = m0 + wm + mt * 16 + lg * 4;
        f32x4 a = acc[mt][nt];
        if (cb < 2048) {
          int hh = cb >> 7, d = (cb & 127) + ll;
          u16* p = qr + ((size_t)hh * S_LEN) * HD + d;
#pragma unroll
          for (int j = 0; j < 4; ++j) p[(size_t)(srow + j) * HD] = f2bf(a[j]);
        } else if (cb < 2560) {
          int hh = (cb - 2048) >> 7, d = ((cb - 2048) & 127) + ll;
          u16* p = kr + ((size_t)hh * S_LEN) * HD + d;
#pragma unroll
          for (int j = 0; j < 4; ++j) p[(size_t)(srow + j) * HD] = f2bf(a[j]);
        } else {
          int hh = (cb - 2560) >> 7, d = ((cb - 2560) & 127) + ll;
          ushort4 pk;
          pk.x = f2bf(a[0]); pk.y = f2bf(a[1]); pk.z = f2bf(a[2]); pk.w = f2bf(a[3]);
          *(ushort4*)(vt + ((size_t)hh * HD + d) * S_LEN + srow) = pk;
        }
      }
    }
  }
}

// ---------------- attention ----------------
// Block-cooperative, double-buffered LDS staging (T3 2-phase). Block = 64 q rows
// x 1 head, 4 waves; all 4 waves share one chunk stream over the block's key
// union [kbeg, bq+63]. K staged [32 rows][256B] slot^=(row&7); V staged packed
// [64 r][128B] (2 d-rows per LDS row) slot^=(r&7). Both via global_load_lds with
// inverse-swizzled GLOBAL source + linear LDS dest (+ swizzled read) per rule 21.
// Per-lane online softmax (swapped QK^T).
__global__ __launch_bounds__(256) void k_attn(const u16* __restrict__ qr, const u16* __restrict__ kr,
                                              const u16* __restrict__ vt, const float* __restrict__ lam,
                                              u16* __restrict__ ao) {
  __shared__ u16 Ks[2][32 * 128];  // 2 x 8KB
  __shared__ u16 Vs[2][64 * 64];   // 2 x 8KB (paired-row: LDS row r holds d=2r,2r+1)
  __shared__ u16 P[4][16 * 40];    // per-wave P^T transpose tile
  const int t = threadIdx.x;
  const int l = t & 63, w = t >> 6;
  const int lg = l >> 4, ll = l & 15;
  const int h = blockIdx.y;
  const int bq = blockIdx.x * 64;
  const int qs = bq + w * 16;
  const int hk = h >> 2;
  const float lm = lam[h];
  const int row = qs + ll;  // this lane's q row

  const u16* Qp = qr + ((size_t)h * S_LEN + qs) * HD;
  const u16* Kp = kr + (size_t)hk * S_LEN * HD;
  const u16* Vp = vt + (size_t)hk * HD * S_LEN;

  // block-union chunk range
  int kbeg = bq - (WIN - 1);
  if (kbeg < 0) kbeg = 0;
  kbeg &= ~31;
  const int nch = (bq + 63 - kbeg + 32) / 32;

  // staging coordinates (computed once; c varies)
  u32 ku[2], krow[2], kslot[2];
#pragma unroll
  for (int j = 0; j < 2; ++j) {
    u32 u = (u32)t * 16u + (u32)j * 4096u;
    ku[j] = u;
    krow[j] = u >> 8;                        // 0..31
    kslot[j] = ((u >> 4) & 15u) ^ (krow[j] & 7u);  // inverse-swizzled 16B slot
  }
  u32 vd[2], vk0[2];
#pragma unroll
  for (int j = 0; j < 2; ++j) {
    u32 u = ku[j];
    u32 r = u >> 7;                          // 0..63
    u32 sl = ((u >> 4) & 7u) ^ (r & 7u);     // logical slot 0..7
    vd[j] = r * 2 + (sl >> 2);               // d row 0..127
    vk0[j] = (sl & 3u) * 8u;                 // key element offset 0..24
  }

  // Q as B-fragment (pre-scaled by QSCALE in rope)
  s16x8 qa[4];
#pragma unroll
  for (int i = 0; i < 4; ++i)
    qa[i] = *(const s16x8*)(Qp + (size_t)ll * HD + i * 32 + lg * 8);

  const f32x4 zero = {0.f, 0.f, 0.f, 0.f};
  float m1 = -1e30f, z1 = 0.f, m2 = -1e30f, z2 = 0.f;

  // ---- pass 1: per-lane online softmax stats (K staged, dbuf) ----
#pragma unroll
  for (int j = 0; j < 2; ++j)
    async16(Kp + (size_t)(kbeg + krow[j]) * HD + kslot[j] * 8, (char*)Ks[0] + ku[j]);
  __syncthreads();

  for (int tc = 0; tc < nch; ++tc) {
    const int c = kbeg + tc * 32;
    if (tc + 1 < nch) {
      const int cn = c + 32;
#pragma unroll
      for (int j = 0; j < 2; ++j)
        async16(Kp + (size_t)(cn + krow[j]) * HD + kslot[j] * 8, (char*)Ks[(tc + 1) & 1] + ku[j]);
    }
    const bool active = (c + 31 >= qs - (WIN - 1)) && (c <= qs + 15);
    if (active) {
      const u16* Kb = Ks[tc & 1];
      float s1v[8], s2v[8];
#pragma unroll
      for (int kt = 0; kt < 2; ++kt) {
        const int kr_ = kt * 16 + ll;
        const u16* kp = Kb + kr_ * 128;
        const u32 sw = (u32)(kr_ & 7);
        s16x8 b0 = *(const s16x8*)(kp + ((lg ^ sw) * 8));
        s16x8 b1 = *(const s16x8*)(kp + (((4 + lg) ^ sw) * 8));
        s16x8 b2 = *(const s16x8*)(kp + (((8 + lg) ^ sw) * 8));
        s16x8 b3 = *(const s16x8*)(kp + (((12 + lg) ^ sw) * 8));
        f32x4 a = __builtin_amdgcn_mfma_f32_16x16x32_bf16(b0, qa[0], zero, 0, 0, 0);
        a = __builtin_amdgcn_mfma_f32_16x16x32_bf16(b1, qa[1], a, 0, 0, 0);
        f32x4 b = __builtin_amdgcn_mfma_f32_16x16x32_bf16(b2, qa[2], zero, 0, 0, 0);
        b = __builtin_amdgcn_mfma_f32_16x16x32_bf16(b3, qa[3], b, 0, 0, 0);
#pragma unroll
        for (int j = 0; j < 4; ++j) { s1v[kt * 4 + j] = a[j]; s2v[kt * 4 + j] = b[j]; }
      }
      const bool full = (c + 31 <= qs) && (c >= qs - 496);  // wave-uniform
      if (!full) {
#pragma unroll
        for (int i = 0; i < 8; ++i) {
          int key = c + (i >> 2) * 16 + lg * 4 + (i & 3);
          bool ok = (key <= row) && (key > row - WIN);
          s1v[i] = ok ? s1v[i] : -1e30f;
          s2v[i] = ok ? s2v[i] : -1e30f;
        }
      }
      float cm1 = s1v[0], cm2 = s2v[0];
#pragma unroll
      for (int i = 1; i < 8; ++i) { cm1 = fmaxf(cm1, s1v[i]); cm2 = fmaxf(cm2, s2v[i]); }
      float nm1 = fmaxf(m1, cm1), nm2 = fmaxf(m2, cm2);
      float acc1 = 0.f, acc2 = 0.f;
      if (full) {
#pragma unroll
        for (int i = 0; i < 8; ++i) {
          acc1 += __builtin_amdgcn_exp2f(s1v[i] - nm1);
          acc2 += __builtin_amdgcn_exp2f(s2v[i] - nm2);
        }
      } else {
#pragma unroll
        for (int i = 0; i < 8; ++i) {
          acc1 += (s1v[i] > -1e29f) ? __builtin_amdgcn_exp2f(s1v[i] - nm1) : 0.f;
          acc2 += (s2v[i] > -1e29f) ? __builtin_amdgcn_exp2f(s2v[i] - nm2) : 0.f;
        }
      }
      z1 = z1 * __builtin_amdgcn_exp2f(m1 - nm1) + acc1;
      z2 = z2 * __builtin_amdgcn_exp2f(m2 - nm2) + acc2;
      m1 = nm1; m2 = nm2;
    }
    __syncthreads();
  }

  // merge the 4 lg-group partials (lanes ll, ll+16, ll+32, ll+48 share q=ll)
#pragma unroll
  for (int mk = 16; mk <= 32; mk <<= 1) {
    float om = __shfl_xor(m1, mk, 64), oz = __shfl_xor(z1, mk, 64);
    float nm = fmaxf(m1, om);
    z1 = z1 * __builtin_amdgcn_exp2f(m1 - nm) + oz * __builtin_amdgcn_exp2f(om - nm);
    m1 = nm;
    om = __shfl_xor(m2, mk, 64); oz = __shfl_xor(z2, mk, 64);
    nm = fmaxf(m2, om);
    z2 = z2 * __builtin_amdgcn_exp2f(m2 - nm) + oz * __builtin_amdgcn_exp2f(om - nm);
    m2 = nm;
  }
  const float rz1 = __builtin_amdgcn_rcpf(z1);
  const float rz2 = __builtin_amdgcn_rcpf(z2);

  // ---- pass 2: recompute scores, diff-combine, PV (K+V staged, dbuf) ----
  f32x4 o[8];
#pragma unroll
  for (int dt = 0; dt < 8; ++dt) o[dt] = zero;
  float dsum = 0.f;

#pragma unroll
  for (int j = 0; j < 2; ++j) {
    async16(Kp + (size_t)(kbeg + krow[j]) * HD + kslot[j] * 8, (char*)Ks[0] + ku[j]);
    async16(Vp + (size_t)vd[j] * S_LEN + kbeg + vk0[j], (char*)Vs[0] + ku[j]);
  }
  __syncthreads();

  for (int tc = 0; tc < nch; ++tc) {
    const int c = kbeg + tc * 32;
    if (tc + 1 < nch) {
      const int cn = c + 32;
#pragma unroll
      for (int j = 0; j < 2; ++j) {
        async16(Kp + (size_t)(cn + krow[j]) * HD + kslot[j] * 8, (char*)Ks[(tc + 1) & 1] + ku[j]);
        async16(Vp + (size_t)vd[j] * S_LEN + cn + vk0[j], (char*)Vs[(tc + 1) & 1] + ku[j]);
      }
    }
    const bool active = (c + 31 >= qs - (WIN - 1)) && (c <= qs + 15);
    if (active) {
      const u16* Kb = Ks[tc & 1];
      const u16* Vb = Vs[tc & 1];
      float s1v[8], s2v[8];
#pragma unroll
      for (int kt = 0; kt < 2; ++kt) {
        const int kr_ = kt * 16 + ll;
        const u16* kp = Kb + kr_ * 128;
        const u32 sw = (u32)(kr_ & 7);
        s16x8 b0 = *(const s16x8*)(kp + ((lg ^ sw) * 8));
        s16x8 b1 = *(const s16x8*)(kp + (((4 + lg) ^ sw) * 8));
        s16x8 b2 = *(const s16x8*)(kp + (((8 + lg) ^ sw) * 8));
        s16x8 b3 = *(const s16x8*)(kp + (((12 + lg) ^ sw) * 8));
        f32x4 a = __builtin_amdgcn_mfma_f32_16x16x32_bf16(b0, qa[0], zero, 0, 0, 0);
        a = __builtin_amdgcn_mfma_f32_16x16x32_bf16(b1, qa[1], a, 0, 0, 0);
        f32x4 b = __builtin_amdgcn_mfma_f32_16x16x32_bf16(b2, qa[2], zero, 0, 0, 0);
        b = __builtin_amdgcn_mfma_f32_16x16x32_bf16(b3, qa[3], b, 0, 0, 0);
#pragma unroll
        for (int j = 0; j < 4; ++j) { s1v[kt * 4 + j] = a[j]; s2v[kt * 4 + j] = b[j]; }
      }
      const bool full = (c + 31 <= qs) && (c >= qs - 496);
      if (!full) {
#pragma unroll
        for (int i = 0; i < 8; ++i) {
          int key = c + (i >> 2) * 16 + lg * 4 + (i & 3);
          bool ok = (key <= row) && (key > row - WIN);
          s1v[i] = ok ? s1v[i] : -1e30f;
          s2v[i] = ok ? s2v[i] : -1e30f;
        }
      }
      float dv[8];
#pragma unroll
      for (int i = 0; i < 8; ++i) {
        float a1 = __builtin_amdgcn_exp2f(s1v[i] - m1) * rz1;
        float a2 = __builtin_amdgcn_exp2f(s2v[i] - m2) * rz2;
        float d = fmaxf(fmaf(-lm, a2, a1), 0.f);
        dv[i] = d;
        dsum += d;
      }
      ushort4 p0, p1;
      p0.x = f2bf(dv[0]); p0.y = f2bf(dv[1]); p0.z = f2bf(dv[2]); p0.w = f2bf(dv[3]);
      p1.x = f2bf(dv[4]); p1.y = f2bf(dv[5]); p1.z = f2bf(dv[6]); p1.w = f2bf(dv[7]);
      *(ushort4*)(&P[w][ll * 40 + lg * 4]) = p0;       // keys kt=0: lg*4..+3
      *(ushort4*)(&P[w][ll * 40 + 16 + lg * 4]) = p1;  // keys kt=1: 16+lg*4..+3
      s16x8 pf = *(const s16x8*)(&P[w][ll * 40 + lg * 8]);
#pragma unroll
      for (int dt = 0; dt < 8; ++dt) {
        const int d = dt * 16 + ll;
        const u32 r = (u32)(d >> 1);
        const u32 sl = (u32)(((d & 1) * 4 + lg)) ^ (r & 7u);
        s16x8 vf = *(const s16x8*)(Vb + r * 64 + sl * 8);
        o[dt] = __builtin_amdgcn_mfma_f32_16x16x32_bf16(pf, vf, o[dt], 0, 0, 0);
      }
    }
    __syncthreads();
  }

  // dsum: merge lg partials, then fetch 1/(sum+eps) for output rows lg*4+j
  dsum += __shfl_xor(dsum, 16, 64);
  dsum += __shfl_xor(dsum, 32, 64);
  const float rds = __builtin_amdgcn_rcpf(dsum + 1e-6f);
  float rdsj[4];
#pragma unroll
  for (int j = 0; j < 4; ++j) rdsj[j] = __shfl(rds, lg * 4 + j, 64);

#pragma unroll
  for (int dt = 0; dt < 8; ++dt) {
#pragma unroll
    for (int j = 0; j < 4; ++j) {
      int srow = qs + lg * 4 + j;
      ao[(size_t)srow * DMODEL + h * HD + dt * 16 + ll] = f2bf(o[dt][j] * rdsj[j]);
    }
  }
}

// ---------------- launch ----------------

extern "C" void kernel_launch(void* const* d_in, const int* in_sizes, int n_in,
                              void* d_out, int out_size, void* d_ws, size_t ws_size,
                              hipStream_t stream) {
  const float* x = (const float*)d_in[0];
  const float* Wq = (const float*)d_in[1];
  const float* Wk = (const float*)d_in[2];
  const float* Wv = (const float*)d_in[3];
  const float* Wo = (const float*)d_in[4];
  const float* lam = (const float*)d_in[5];
  float* out = (float*)d_out;

  char* ws = (char*)d_ws;
  u16* xb = (u16*)(ws);                               // 8 MB  [2048][2048]
  u16* WT = (u16*)(ws + (8u << 20));                  // 12 MB [3072][2048] (Wq^T|Wk^T|Wv^T)
  u16* WoT = (u16*)(ws + (20u << 20));                // 8 MB  [2048][2048]
  u16* qr = (u16*)(ws + (28u << 20));                 // 8 MB  [16][2048][128]
  u16* kr = (u16*)(ws + (36u << 20));                 // 2 MB  [4][2048][128]
  u16* vt = (u16*)(ws + (38u << 20));                 // 2 MB  [4][128][2048]
  u16* ao = (u16*)(ws + (40u << 20));                 // 8 MB  [2048][2048]
  float2* cs = (float2*)(ws + (48u << 20));           // 1 MB  [2048][64]

  k_rope_table<<<S_LEN, 64, 0, stream>>>(cs);
  k_convert_bf16<<<4096, 256, 0, stream>>>(x, xb, (S_LEN * DMODEL) / 4);

  dim3 tb(32, 8);
  k_transpose_bf16<<<dim3(2048 / 32, 2048 / 32), tb, 0, stream>>>(Wq, WT, 2048, 2048);
  k_transpose_bf16<<<dim3(512 / 32, 2048 / 32), tb, 0, stream>>>(Wk, WT + (size_t)2048 * 2048, 2048, 512);
  k_transpose_bf16<<<dim3(512 / 32, 2048 / 32), tb, 0, stream>>>(Wv, WT + (size_t)2560 * 2048, 2048, 512);
  k_transpose_bf16<<<dim3(2048 / 32, 2048 / 32), tb, 0, stream>>>(Wo, WoT, 2048, 2048);

  k_gemm<0><<<dim3(32, 24), 256, 0, stream>>>(xb, WT, nullptr, 2048, 3072, qr, kr, vt);

  // Q pre-scaled by 0.125*log2(e) -> QK^T scores land directly in exp2 domain
  k_rope_apply<<<(NH * S_LEN * 64) / 256, 256, 0, stream>>>(qr, cs, NH * S_LEN, QSCALE);
  k_rope_apply<<<(NKV * S_LEN * 64) / 256, 256, 0, stream>>>(kr, cs, NKV * S_LEN, 1.0f);

  k_attn<<<dim3(S_LEN / 64, NH), 256, 0, stream>>>(qr, kr, vt, lam, ao);

  k_gemm<1><<<dim3(32, 16), 256, 0, stream>>>(ao, WoT, out, 2048, 2048, nullptr, nullptr, nullptr);
}

// Round 5
// 128.429 us; speedup vs baseline: 1.8729x; 1.2139x over previous
//
#include <hip/hip_runtime.h>

typedef unsigned int u32;
typedef unsigned short u16;
typedef __attribute__((ext_vector_type(4))) float f32x4;
typedef __attribute__((ext_vector_type(8))) short s16x8;

#define S_LEN 2048
#define DMODEL 2048
#define NH 16
#define NKV 4
#define HD 128
#define WIN 512
// 0.125 (1/sqrt(64)) * log2(e): folds score scale + exp2-domain conversion into Q
#define QSCALE 0.18033688011112042f

#define WAIT_VMCNT4 asm volatile("s_waitcnt vmcnt(4)" ::: "memory")
#define WAIT_VMCNT0 asm volatile("s_waitcnt vmcnt(0)" ::: "memory")

__device__ __forceinline__ u16 f2bf(float f) {
  union { float f; u32 u; } v; v.f = f;
  u32 r = v.u + 0x7FFFu + ((v.u >> 16) & 1u);
  return (u16)(r >> 16);
}
__device__ __forceinline__ float bf2f(u16 h) {
  union { u32 u; float f; } v; v.u = ((u32)h) << 16;
  return v.f;
}

__device__ __forceinline__ void async16(const void* g, void* l) {
  __builtin_amdgcn_global_load_lds((const __attribute__((address_space(1))) void*)g,
                                   (__attribute__((address_space(3))) void*)l, 16, 0, 0);
}

// ---------------- prep kernels ----------------

__global__ void k_rope_table(float2* __restrict__ cs) {
  int s = blockIdx.x, d = threadIdx.x;  // d in [0,64)
  float invf = expf(-((float)(2 * d) / (float)HD) * logf(10000.0f));
  float fr = (float)s * invf;
  float sv, cv;
  sincosf(fr, &sv, &cv);
  cs[s * 64 + d] = make_float2(cv, sv);
}

__global__ void k_convert_bf16(const float* __restrict__ src, u16* __restrict__ dst, int n4) {
  int i = blockIdx.x * blockDim.x + threadIdx.x;
  if (i >= n4) return;
  float4 v = ((const float4*)src)[i];
  ushort4 o;
  o.x = f2bf(v.x); o.y = f2bf(v.y); o.z = f2bf(v.z); o.w = f2bf(v.w);
  ((ushort4*)dst)[i] = o;
}

// all 4 weight transposes in one launch. tiles: Wq 4096 | Wk 1024 | Wv 1024 | Wo 4096
__global__ __launch_bounds__(256) void k_transpose_all(const float* __restrict__ Wq,
                                                       const float* __restrict__ Wk,
                                                       const float* __restrict__ Wv,
                                                       const float* __restrict__ Wo,
                                                       u16* __restrict__ WT,
                                                       u16* __restrict__ WoT) {
  __shared__ float tile[32][33];
  const int bid = blockIdx.x;
  const float* src;
  u16* dst;
  int N, nt, kt;
  if (bid < 4096) {
    src = Wq; dst = WT; N = 2048; nt = bid & 63; kt = bid >> 6;
  } else if (bid < 5120) {
    int i = bid - 4096;
    src = Wk; dst = WT + (size_t)2048 * 2048; N = 512; nt = i & 15; kt = i >> 4;
  } else if (bid < 6144) {
    int i = bid - 5120;
    src = Wv; dst = WT + (size_t)2560 * 2048; N = 512; nt = i & 15; kt = i >> 4;
  } else {
    int i = bid - 6144;
    src = Wo; dst = WoT; N = 2048; nt = i & 63; kt = i >> 6;
  }
  const int tx = threadIdx.x & 31, ty = threadIdx.x >> 5;
  const int n0 = nt * 32, k0 = kt * 32;
#pragma unroll
  for (int i = 0; i < 4; ++i)
    tile[ty + 8 * i][tx] = src[(size_t)(k0 + ty + 8 * i) * N + n0 + tx];
  __syncthreads();
#pragma unroll
  for (int i = 0; i < 4; ++i)
    dst[(size_t)(n0 + ty + 8 * i) * 2048 + k0 + tx] = f2bf(tile[tx][ty + 8 * i]);
}

// rope on q (scaled by QSCALE) and k (scale 1) in one launch.
__global__ void k_rope_apply2(u16* __restrict__ qr, u16* __restrict__ kr,
                              const float2* __restrict__ cs) {
  int i = blockIdx.x * blockDim.x + threadIdx.x;
  int rowg = i >> 6, d = i & 63;
  const bool isq = rowg < NH * S_LEN;
  u16* p = isq ? qr + (size_t)rowg * HD : kr + (size_t)(rowg - NH * S_LEN) * HD;
  const float scale = isq ? QSCALE : 1.0f;
  int s = rowg & (S_LEN - 1);
  float2 c = cs[s * 64 + d];
  float a = bf2f(p[d]), b = bf2f(p[d + 64]);
  p[d]      = f2bf((a * c.x - b * c.y) * scale);
  p[d + 64] = f2bf((b * c.x + a * c.y) * scale);
}

// ---------------- GEMM ----------------
// A [M][K] bf16 row-major, BT [N][K] bf16. 64x128 tile, BK=64, 4 waves (2x2 of
// 32x64), double-buffered LDS (T3-min: stage t+1 before compute t, one barrier
// per K-step), chunked XCD swizzle. LDS rows 128B (8 slots), XOR-swizzle row&7.
// MODE 0: scatter epilogue -> qr[h][s][d], kr[h][s][d], vt[h][d][s]
// MODE 1: plain fp32 C[M][N]

template <int MODE>
__global__ __launch_bounds__(256) void k_gemm(const u16* __restrict__ A, const u16* __restrict__ BT,
                                              float* __restrict__ Cf, int K, int N,
                                              u16* __restrict__ qr, u16* __restrict__ kr,
                                              u16* __restrict__ vt) {
  // A rows 0..63, B rows 64..191; each row 64 u16 = 128B; 24KB per buffer
  __shared__ u16 S[2][192 * 64];
  const int t = threadIdx.x;
  const int l = t & 63, w = t >> 6;
  const int lg = l >> 4, ll = l & 15;

  // chunked XCD swizzle (bijective: nwg % 8 == 0 for both call sites)
  const u32 nwg = gridDim.x * gridDim.y;
  const u32 bid = blockIdx.y * gridDim.x + blockIdx.x;  // m-fastest linearization
  const u32 sid = (bid & 7u) * (nwg >> 3) + (bid >> 3);
  const int m0 = (int)(sid % gridDim.x) * 64;
  const int n0 = (int)(sid / gridDim.x) * 128;

  const int wm = (w >> 1) * 32, wn = (w & 1) * 64;

  // staging: thread t, issue j covers LDS bytes u = t*16 + j*4096 (j=0..5).
  // row = u>>7 (0..191). 16B slot: phys = (u>>4)&7, logical = phys ^ (row&7).
  const u16* gp[6];
  u32 lo[6];
#pragma unroll
  for (int j = 0; j < 6; ++j) {
    u32 u = (u32)t * 16u + (u32)j * 4096u;
    u32 row = u >> 7;
    u32 slot = ((u >> 4) & 7u) ^ (row & 7u);
    lo[j] = u;
    gp[j] = (row < 64 ? A + (size_t)(m0 + (int)row) * K
                      : BT + (size_t)(n0 + (int)(row - 64)) * K) + slot * 8;
  }
  auto stage = [&](int b, int k0) {
#pragma unroll
    for (int j = 0; j < 6; ++j) async16(gp[j] + k0, (char*)S[b] + lo[j]);
  };

  f32x4 acc[2][4];
#pragma unroll
  for (int i = 0; i < 2; ++i)
#pragma unroll
    for (int j = 0; j < 4; ++j) acc[i][j] = (f32x4){0.f, 0.f, 0.f, 0.f};

  stage(0, 0);
  __syncthreads();

  const int nit = K / 64;
#pragma unroll 2
  for (int it = 0; it < nit; ++it) {
    const int cur = it & 1;
    if (it + 1 < nit) stage(cur ^ 1, (it + 1) * 64);  // loads fly under compute

    s16x8 af[2][2], bq[4][2];
#pragma unroll
    for (int mt = 0; mt < 2; ++mt) {
      u32 r = (u32)(wm + mt * 16 + ll);
#pragma unroll
      for (int ks = 0; ks < 2; ++ks)
        af[mt][ks] = *(const s16x8*)((const char*)S[cur] + r * 128u +
                                     ((((u32)(ks * 4 + lg)) ^ (r & 7u)) * 16u));
    }
#pragma unroll
    for (int nt = 0; nt < 4; ++nt) {
      u32 r = (u32)(64 + wn + nt * 16 + ll);
#pragma unroll
      for (int ks = 0; ks < 2; ++ks)
        bq[nt][ks] = *(const s16x8*)((const char*)S[cur] + r * 128u +
                                     ((((u32)(ks * 4 + lg)) ^ (r & 7u)) * 16u));
    }
#pragma unroll
    for (int ks = 0; ks < 2; ++ks)
#pragma unroll
      for (int mt = 0; mt < 2; ++mt)
#pragma unroll
        for (int nt = 0; nt < 4; ++nt)
          acc[mt][nt] = __builtin_amdgcn_mfma_f32_16x16x32_bf16(af[mt][ks], bq[nt][ks],
                                                                acc[mt][nt], 0, 0, 0);
    __syncthreads();  // compiler drains vmcnt(0) here (after compute)
  }

  if (MODE == 1) {
#pragma unroll
    for (int mt = 0; mt < 2; ++mt) {
      int srow = m0 + wm + mt * 16 + lg * 4;
#pragma unroll
      for (int nt = 0; nt < 4; ++nt) {
        int col = n0 + wn + nt * 16 + ll;
        f32x4 a = acc[mt][nt];
#pragma unroll
        for (int j = 0; j < 4; ++j) Cf[(size_t)(srow + j) * N + col] = a[j];
      }
    }
  } else {
#pragma unroll
    for (int nt = 0; nt < 4; ++nt) {
      int cb = n0 + wn + nt * 16;  // wave-uniform
#pragma unroll
      for (int mt = 0; mt < 2; ++mt) {
        int srow = m0 + wm + mt * 16 + lg * 4;
        f32x4 a = acc[mt][nt];
        if (cb < 2048) {
          int hh = cb >> 7, d = (cb & 127) + ll;
          u16* p = qr + ((size_t)hh * S_LEN) * HD + d;
#pragma unroll
          for (int j = 0; j < 4; ++j) p[(size_t)(srow + j) * HD] = f2bf(a[j]);
        } else if (cb < 2560) {
          int hh = (cb - 2048) >> 7, d = ((cb - 2048) & 127) + ll;
          u16* p = kr + ((size_t)hh * S_LEN) * HD + d;
#pragma unroll
          for (int j = 0; j < 4; ++j) p[(size_t)(srow + j) * HD] = f2bf(a[j]);
        } else {
          int hh = (cb - 2560) >> 7, d = ((cb - 2560) & 127) + ll;
          ushort4 pk;
          pk.x = f2bf(a[0]); pk.y = f2bf(a[1]); pk.z = f2bf(a[2]); pk.w = f2bf(a[3]);
          *(ushort4*)(vt + ((size_t)hh * HD + d) * S_LEN + srow) = pk;
        }
      }
    }
  }
}

// ---------------- attention ----------------
// KVBLK=64, no-max online-Z softmax (scores bounded; exp2-domain safe in fp32).
// Pass 1: 4-buffer K staging, counted vmcnt(4) + raw s_barrier (loads span
// barriers, 2-ahead prefetch). Pass 2: 2-buffer K+V, T3-min (__syncthreads;
// stage next; compute). Per-lane key-local scores via swapped mfma(K,Q).
__global__ __launch_bounds__(256) void k_attn(const u16* __restrict__ qr, const u16* __restrict__ kr,
                                              const u16* __restrict__ vt, const float* __restrict__ lam,
                                              u16* __restrict__ ao) {
  __shared__ u16 KV[4][64 * 128];  // 4 x 16KB. pass1: K bufs 0..3; pass2: K 0..1, V 2..3
  __shared__ u16 P[4][16 * 72];    // per-wave P^T tile, row stride 72 u16 (144B)
  const int t = threadIdx.x;
  const int l = t & 63, w = t >> 6;
  const int lg = l >> 4, ll = l & 15;
  const int h = blockIdx.y;
  const int bq = blockIdx.x * 64;
  const int qs = bq + w * 16;
  const int hk = h >> 2;
  const int row = qs + ll;  // this lane's q row

  const u16* Qp = qr + ((size_t)h * S_LEN + qs) * HD;
  const u16* Kp = kr + (size_t)hk * S_LEN * HD;
  const u16* Vp = vt + (size_t)hk * HD * S_LEN;

  int kbeg = bq - (WIN - 1);
  if (kbeg < 0) kbeg = 0;
  kbeg &= ~63;
  const int nch = (bq + 63 - kbeg) / 64 + 1;

  // K staging coords: u = t*16 + j*4096; row=u>>8 (0..63, 256B rows, 16 slots);
  // logical slot = phys ^ (row&7).
  u32 ku[4], krow[4], kslot[4];
#pragma unroll
  for (int j = 0; j < 4; ++j) {
    u32 u = (u32)t * 16u + (u32)j * 4096u;
    ku[j] = u;
    krow[j] = u >> 8;
    kslot[j] = ((u >> 4) & 15u) ^ (krow[j] & 7u);
  }
  // V staging coords: row d = u>>7 (0..127, 128B rows, 8 slots)
  u32 vd[4], vs[4];
#pragma unroll
  for (int j = 0; j < 4; ++j) {
    u32 u = ku[j];
    vd[j] = u >> 7;
    vs[j] = ((u >> 4) & 7u) ^ (vd[j] & 7u);
  }

  // Q as B-fragment (pre-scaled by QSCALE in rope)
  s16x8 qa[4];
#pragma unroll
  for (int i = 0; i < 4; ++i)
    qa[i] = *(const s16x8*)(Qp + (size_t)ll * HD + i * 32 + lg * 8);

  const f32x4 zero = {0.f, 0.f, 0.f, 0.f};
  float z1 = 0.f, z2 = 0.f;

  // ---- pass 1: Z sums (4-buf K, counted vmcnt, raw barrier) ----
  {
#pragma unroll
    for (int j = 0; j < 4; ++j)
      async16(Kp + (size_t)(kbeg + krow[j]) * HD + kslot[j] * 8, (char*)KV + ku[j]);
    const int c1 = kbeg + (nch > 1 ? 64 : 0);
#pragma unroll
    for (int j = 0; j < 4; ++j)
      async16(Kp + (size_t)(c1 + krow[j]) * HD + kslot[j] * 8, (char*)KV + 16384 + ku[j]);
  }

  for (int tc = 0; tc < nch; ++tc) {
    WAIT_VMCNT4;                    // own prev-prev stage landed (in-order vmem)
    __builtin_amdgcn_s_barrier();   // all waves' -> chunk tc fully in LDS
    {
      int c2i = tc + 2; if (c2i > nch - 1) c2i = nch - 1;  // clamped (uniform count)
      const int c2 = kbeg + c2i * 64;
      char* dst = (char*)KV + (size_t)((tc + 2) & 3) * 16384;
#pragma unroll
      for (int j = 0; j < 4; ++j)
        async16(Kp + (size_t)(c2 + krow[j]) * HD + kslot[j] * 8, dst + ku[j]);
    }
    const int c = kbeg + tc * 64;
    const bool active = (c + 63 >= qs - (WIN - 1)) && (c <= qs + 15);
    if (active) {
      const u16* Kb = (const u16*)((const char*)KV + (size_t)(tc & 3) * 16384);
      const bool full = (c + 63 <= qs) && (c >= qs - 496);
      float acc1 = 0.f, acc2 = 0.f;
#pragma unroll
      for (int kt = 0; kt < 4; ++kt) {
        const int kbase = c + kt * 16;
        if (kbase > qs + 15 || kbase + 15 < qs - (WIN - 1)) continue;  // uniform skip
        const int kr_ = kt * 16 + ll;
        const u16* kp = Kb + kr_ * 128;
        const u32 sw = (u32)(kr_ & 7);
        s16x8 b0 = *(const s16x8*)(kp + ((lg ^ sw) * 8));
        s16x8 b1 = *(const s16x8*)(kp + (((4 + lg) ^ sw) * 8));
        s16x8 b2 = *(const s16x8*)(kp + (((8 + lg) ^ sw) * 8));
        s16x8 b3 = *(const s16x8*)(kp + (((12 + lg) ^ sw) * 8));
        f32x4 a = __builtin_amdgcn_mfma_f32_16x16x32_bf16(b0, qa[0], zero, 0, 0, 0);
        a = __builtin_amdgcn_mfma_f32_16x16x32_bf16(b1, qa[1], a, 0, 0, 0);
        f32x4 b = __builtin_amdgcn_mfma_f32_16x16x32_bf16(b2, qa[2], zero, 0, 0, 0);
        b = __builtin_amdgcn_mfma_f32_16x16x32_bf16(b3, qa[3], b, 0, 0, 0);
        if (!full) {
#pragma unroll
          for (int j = 0; j < 4; ++j) {
            int key = kbase + lg * 4 + j;
            bool ok = (key <= row) && (key > row - WIN);
            a[j] = ok ? a[j] : -1e30f;
            b[j] = ok ? b[j] : -1e30f;
          }
        }
#pragma unroll
        for (int j = 0; j < 4; ++j) {
          acc1 += __builtin_amdgcn_exp2f(a[j]);  // exp2(-1e30) flushes to 0
          acc2 += __builtin_amdgcn_exp2f(b[j]);
        }
      }
      z1 += acc1; z2 += acc2;
    }
  }

  __syncthreads();  // drains all in-flight pass-1 stages + syncs

  // merge the 4 lg-group partials (lanes ll, ll+16, ll+32, ll+48 share q=ll)
  z1 += __shfl_xor(z1, 16, 64); z1 += __shfl_xor(z1, 32, 64);
  z2 += __shfl_xor(z2, 16, 64); z2 += __shfl_xor(z2, 32, 64);
  const float l2z1 = __builtin_amdgcn_logf(z1);  // v_log_f32 = log2
  const float l2z2 = __builtin_amdgcn_logf(z2);
  const float lm = lam[h];

  // ---- pass 2: diff-combine + PV (2-buf K in KV[0..1], V in KV[2..3]) ----
  f32x4 o[8];
#pragma unroll
  for (int dt = 0; dt < 8; ++dt) o[dt] = zero;
  float dsum = 0.f;
  u16* Pw = &P[w][0];

#pragma unroll
  for (int j = 0; j < 4; ++j) {
    async16(Kp + (size_t)(kbeg + krow[j]) * HD + kslot[j] * 8, (char*)KV + ku[j]);
    async16(Vp + (size_t)vd[j] * S_LEN + kbeg + vs[j] * 8, (char*)KV + 32768 + ku[j]);
  }

  for (int tc = 0; tc < nch; ++tc) {
    __syncthreads();  // drain (vmcnt 0) + barrier: chunk tc ready
    {
      int c1i = tc + 1; if (c1i > nch - 1) c1i = nch - 1;
      const int cn = kbeg + c1i * 64;
      const u32 b = (u32)((tc + 1) & 1);
#pragma unroll
      for (int j = 0; j < 4; ++j) {
        async16(Kp + (size_t)(cn + krow[j]) * HD + kslot[j] * 8,
                (char*)KV + b * 16384 + ku[j]);
        async16(Vp + (size_t)vd[j] * S_LEN + cn + vs[j] * 8,
                (char*)KV + 32768 + b * 16384 + ku[j]);
      }
    }
    const int c = kbeg + tc * 64;
    const bool active = (c + 63 >= qs - (WIN - 1)) && (c <= qs + 15);
    if (active) {
      const u16* Kb = (const u16*)((const char*)KV + (size_t)(tc & 1) * 16384);
      const u16* Vb = (const u16*)((const char*)KV + 32768 + (size_t)(tc & 1) * 16384);
      const bool full = (c + 63 <= qs) && (c >= qs - 496);
#pragma unroll
      for (int kt = 0; kt < 4; ++kt) {
        const int kbase = c + kt * 16;
        if (kbase > qs + 15 || kbase + 15 < qs - (WIN - 1)) {
          ushort4 zz; zz.x = zz.y = zz.z = zz.w = 0;
          *(ushort4*)(&Pw[ll * 72 + kt * 16 + lg * 4]) = zz;
          continue;
        }
        const int kr_ = kt * 16 + ll;
        const u16* kp = Kb + kr_ * 128;
        const u32 sw = (u32)(kr_ & 7);
        s16x8 b0 = *(const s16x8*)(kp + ((lg ^ sw) * 8));
        s16x8 b1 = *(const s16x8*)(kp + (((4 + lg) ^ sw) * 8));
        s16x8 b2 = *(const s16x8*)(kp + (((8 + lg) ^ sw) * 8));
        s16x8 b3 = *(const s16x8*)(kp + (((12 + lg) ^ sw) * 8));
        f32x4 a = __builtin_amdgcn_mfma_f32_16x16x32_bf16(b0, qa[0], zero, 0, 0, 0);
        a = __builtin_amdgcn_mfma_f32_16x16x32_bf16(b1, qa[1], a, 0, 0, 0);
        f32x4 b = __builtin_amdgcn_mfma_f32_16x16x32_bf16(b2, qa[2], zero, 0, 0, 0);
        b = __builtin_amdgcn_mfma_f32_16x16x32_bf16(b3, qa[3], b, 0, 0, 0);
        if (!full) {
#pragma unroll
          for (int j = 0; j < 4; ++j) {
            int key = kbase + lg * 4 + j;
            bool ok = (key <= row) && (key > row - WIN);
            a[j] = ok ? a[j] : -1e30f;
            b[j] = ok ? b[j] : -1e30f;
          }
        }
        float dv[4];
        float dl = 0.f;
#pragma unroll
        for (int j = 0; j < 4; ++j) {
          float a1 = __builtin_amdgcn_exp2f(a[j] - l2z1);
          float a2 = __builtin_amdgcn_exp2f(b[j] - l2z2);
          float d = fmaxf(fmaf(-lm, a2, a1), 0.f);
          dv[j] = d;
          dl += d;
        }
        dsum += dl;
        ushort4 p;
        p.x = f2bf(dv[0]); p.y = f2bf(dv[1]); p.z = f2bf(dv[2]); p.w = f2bf(dv[3]);
        *(ushort4*)(&Pw[ll * 72 + kt * 16 + lg * 4]) = p;
      }
      // per-wave LDS transpose round-trip (compiler inserts lgkmcnt waits)
      s16x8 pf0 = *(const s16x8*)(&Pw[ll * 72 + lg * 8]);
      s16x8 pf1 = *(const s16x8*)(&Pw[ll * 72 + 32 + lg * 8]);
#pragma unroll
      for (int dt = 0; dt < 8; ++dt) {
        const int d = dt * 16 + ll;
        const u32 swv = (u32)(d & 7);
        s16x8 vf0 = *(const s16x8*)(Vb + (size_t)d * 64 + ((lg ^ swv) * 8));
        s16x8 vf1 = *(const s16x8*)(Vb + (size_t)d * 64 + (((4 + lg) ^ swv) * 8));
        o[dt] = __builtin_amdgcn_mfma_f32_16x16x32_bf16(pf0, vf0, o[dt], 0, 0, 0);
        o[dt] = __builtin_amdgcn_mfma_f32_16x16x32_bf16(pf1, vf1, o[dt], 0, 0, 0);
      }
    }
  }
  WAIT_VMCNT0;  // drain trailing redundant stage before kernel end

  // dsum: merge lg partials, then fetch 1/(sum+eps) for output rows lg*4+j
  dsum += __shfl_xor(dsum, 16, 64);
  dsum += __shfl_xor(dsum, 32, 64);
  const float rds = __builtin_amdgcn_rcpf(dsum + 1e-6f);
  float rdsj[4];
#pragma unroll
  for (int j = 0; j < 4; ++j) rdsj[j] = __shfl(rds, lg * 4 + j, 64);

#pragma unroll
  for (int dt = 0; dt < 8; ++dt) {
#pragma unroll
    for (int j = 0; j < 4; ++j) {
      int srow = qs + lg * 4 + j;
      ao[(size_t)srow * DMODEL + h * HD + dt * 16 + ll] = f2bf(o[dt][j] * rdsj[j]);
    }
  }
}

// ---------------- launch ----------------

extern "C" void kernel_launch(void* const* d_in, const int* in_sizes, int n_in,
                              void* d_out, int out_size, void* d_ws, size_t ws_size,
                              hipStream_t stream) {
  const float* x = (const float*)d_in[0];
  const float* Wq = (const float*)d_in[1];
  const float* Wk = (const float*)d_in[2];
  const float* Wv = (const float*)d_in[3];
  const float* Wo = (const float*)d_in[4];
  const float* lam = (const float*)d_in[5];
  float* out = (float*)d_out;

  char* ws = (char*)d_ws;
  u16* xb = (u16*)(ws);                               // 8 MB  [2048][2048]
  u16* WT = (u16*)(ws + (8u << 20));                  // 12 MB [3072][2048] (Wq^T|Wk^T|Wv^T)
  u16* WoT = (u16*)(ws + (20u << 20));                // 8 MB  [2048][2048]
  u16* qr = (u16*)(ws + (28u << 20));                 // 8 MB  [16][2048][128]
  u16* kr = (u16*)(ws + (36u << 20));                 // 2 MB  [4][2048][128]
  u16* vt = (u16*)(ws + (38u << 20));                 // 2 MB  [4][128][2048]
  u16* ao = (u16*)(ws + (40u << 20));                 // 8 MB  [2048][2048]
  float2* cs = (float2*)(ws + (48u << 20));           // 1 MB  [2048][64]

  k_rope_table<<<S_LEN, 64, 0, stream>>>(cs);
  k_convert_bf16<<<4096, 256, 0, stream>>>(x, xb, (S_LEN * DMODEL) / 4);

  k_transpose_all<<<10240, 256, 0, stream>>>(Wq, Wk, Wv, Wo, WT, WoT);

  k_gemm<0><<<dim3(32, 24), 256, 0, stream>>>(xb, WT, nullptr, 2048, 3072, qr, kr, vt);

  // Q pre-scaled by 0.125*log2(e) -> QK^T scores land directly in exp2 domain
  k_rope_apply2<<<((NH + NKV) * S_LEN * 64) / 256, 256, 0, stream>>>(qr, kr, cs);

  k_attn<<<dim3(S_LEN / 64, NH), 256, 0, stream>>>(qr, kr, vt, lam, ao);

  k_gemm<1><<<dim3(32, 16), 256, 0, stream>>>(ao, WoT, out, 2048, 2048, nullptr, nullptr, nullptr);
}